// Round 3
// baseline (24874.046 us; speedup 1.0000x reference)
//
#include <hip/hip_runtime.h>
#include <hip/hip_bf16.h>
#include <cstdint>
#include <cstddef>

// Problem constants (fixed by reference)
#define B_    8
#define T_    256
#define D_    512
#define W_    32
#define L_    4
#define A_    6
#define H_    8
#define DH_   64
#define NWIN  (B_*T_)        // 2048 windows
#define NTOK  (NWIN*W_)      // 65536 token rows

// Fallback workspace (allocated at dlopen, OUTSIDE kernel_launch/graph capture)
// in case ws_size is too small for x (128 MiB) + chunk scratch.
static float* g_fallback = nullptr;
#define SCR_BYTES_PER_NC  ((size_t)32 * 2048 * 4)            // 256 KiB per window
#define X_BYTES           ((size_t)NTOK * D_ * 4)            // 128 MiB
__attribute__((constructor)) static void alloc_fallback() {
    (void)hipMalloc((void**)&g_fallback, X_BYTES + 256 * SCR_BYTES_PER_NC);
}

// ---------------------------------------------------------------------------
// build_x: x[n*32+w, :] = feats[b, max(t+w-31,0), :] + pos_embed[w, :]
// ---------------------------------------------------------------------------
__global__ __launch_bounds__(256) void build_x_kernel(
    const float* __restrict__ feats,  // (B,T,D)
    const float* __restrict__ pos,    // (1,W,D)
    float* __restrict__ x)            // (NTOK, D)
{
    int gid   = blockIdx.x * 256 + threadIdx.x;   // over NTOK * (D/4)
    int token = gid >> 7;                          // D/4 = 128
    int c4    = (gid & 127) * 4;
    int w     = token & (W_-1);
    int n     = token >> 5;
    int t     = n & (T_-1);
    int b     = n >> 8;                            // T_=256
    int frame = t + w - (W_-1); if (frame < 0) frame = 0;
    const float4 f = *(const float4*)(feats + ((size_t)(b*T_ + frame)*D_ + c4));
    const float4 p = *(const float4*)(pos   + ((size_t)w*D_ + c4));
    float4 r; r.x = f.x+p.x; r.y = f.y+p.y; r.z = f.z+p.z; r.w = f.w+p.w;
    *(float4*)(x + (size_t)token*D_ + c4) = r;
}

// ---------------------------------------------------------------------------
// fp32 GEMM: C = A(MxK) @ Wt(NxK)^T + bias (+ resid) (opt ReLU)
// Tile 128x64, BK=16, 256 threads, 8x4 acc per thread.
// NOTE: C may alias resid (in-place residual update): each (m,n) is read
// (resid) and written (C) by the same thread only -> no cross-thread hazard.
// ---------------------------------------------------------------------------
template<bool RELU, bool RESID>
__global__ __launch_bounds__(256) void gemm_kernel(
    const float* __restrict__ A,
    const float* __restrict__ Wt,
    const float* __restrict__ bias,
    const float* resid,
    float* C,
    int M, int N, int K)
{
    const int BM = 128, BN = 64, BK = 16;
    __shared__ float As[BK][BM + 4];
    __shared__ float Bs[BK][BN + 4];

    const int tid = threadIdx.x;
    const int m0  = blockIdx.y * BM;
    const int n0  = blockIdx.x * BN;
    const int tx  = tid & 15;    // n-dir
    const int ty  = tid >> 4;    // m-dir

    float acc[8][4];
#pragma unroll
    for (int i = 0; i < 8; ++i)
#pragma unroll
        for (int j = 0; j < 4; ++j) acc[i][j] = 0.f;

    const int la_r = tid >> 2;         // 0..63
    const int la_k = (tid & 3) * 4;    // 0,4,8,12

    for (int k0 = 0; k0 < K; k0 += BK) {
        float4 a0 = *(const float4*)(A  + (size_t)(m0 + la_r)      * K + k0 + la_k);
        float4 a1 = *(const float4*)(A  + (size_t)(m0 + la_r + 64) * K + k0 + la_k);
        float4 b0 = *(const float4*)(Wt + (size_t)(n0 + la_r)      * K + k0 + la_k);
        As[la_k + 0][la_r]      = a0.x;
        As[la_k + 1][la_r]      = a0.y;
        As[la_k + 2][la_r]      = a0.z;
        As[la_k + 3][la_r]      = a0.w;
        As[la_k + 0][la_r + 64] = a1.x;
        As[la_k + 1][la_r + 64] = a1.y;
        As[la_k + 2][la_r + 64] = a1.z;
        As[la_k + 3][la_r + 64] = a1.w;
        Bs[la_k + 0][la_r]      = b0.x;
        Bs[la_k + 1][la_r]      = b0.y;
        Bs[la_k + 2][la_r]      = b0.z;
        Bs[la_k + 3][la_r]      = b0.w;
        __syncthreads();

#pragma unroll
        for (int kk = 0; kk < BK; ++kk) {
            float a[8], b[4];
#pragma unroll
            for (int i = 0; i < 8; ++i) a[i] = As[kk][ty*8 + i];
#pragma unroll
            for (int j = 0; j < 4; ++j) b[j] = Bs[kk][tx*4 + j];
#pragma unroll
            for (int i = 0; i < 8; ++i)
#pragma unroll
                for (int j = 0; j < 4; ++j) acc[i][j] += a[i] * b[j];
        }
        __syncthreads();
    }

#pragma unroll
    for (int i = 0; i < 8; ++i) {
        int m = m0 + ty*8 + i;
#pragma unroll
        for (int j = 0; j < 4; ++j) {
            int n = n0 + tx*4 + j;
            float c = acc[i][j] + bias[n];
            if (RESID) c += resid[(size_t)m * N + n];
            if (RELU)  c = fmaxf(c, 0.f);
            C[(size_t)m * N + n] = c;
        }
    }
}

// ---------------------------------------------------------------------------
// Attention: one block per (window n(local), head h). W=32, dh=64, causal.
// qkv: (NC*32, 1536) rows = n*32+w; q cols [0,512), k [512,1024), v [1024,1536)
// ctx: (NC*32, 512)
// ---------------------------------------------------------------------------
__global__ __launch_bounds__(256) void attn_kernel(
    const float* __restrict__ qkv,
    float* __restrict__ ctx)
{
    const int n = blockIdx.x;
    const int h = blockIdx.y;
    __shared__ float q[W_][DH_];
    __shared__ float k[W_][DH_];
    __shared__ float v[W_][DH_];
    __shared__ float s[W_][W_ + 1];

    const int tid = threadIdx.x;
    {   // load q,k,v: thread -> row tid>>3, 8 cols
        int r  = tid >> 3;
        int c0 = (tid & 7) * 8;
        const float* base = qkv + (size_t)(n*W_ + r) * (3*D_) + h*DH_ + c0;
#pragma unroll
        for (int j = 0; j < 8; ++j) {
            q[r][c0 + j] = base[j];
            k[r][c0 + j] = base[D_ + j];
            v[r][c0 + j] = base[2*D_ + j];
        }
    }
    __syncthreads();

    const int i  = tid >> 3;          // score/ctx row
    {   // scores: 4 cols per thread
        int j0 = (tid & 7) * 4;
#pragma unroll
        for (int jj = 0; jj < 4; ++jj) {
            int j = j0 + jj;
            float d = 0.f;
#pragma unroll
            for (int kk = 0; kk < DH_; ++kk) d += q[i][kk] * k[j][kk];
            s[i][j] = (j <= i) ? d * 0.125f : -1e30f;
        }
    }
    __syncthreads();

    if (tid < W_) {   // softmax, one row per thread
        float mx = -1e30f;
#pragma unroll
        for (int j = 0; j < W_; ++j) mx = fmaxf(mx, s[tid][j]);
        float sum = 0.f;
#pragma unroll
        for (int j = 0; j < W_; ++j) { float e = __expf(s[tid][j] - mx); s[tid][j] = e; sum += e; }
        float inv = 1.f / sum;
#pragma unroll
        for (int j = 0; j < W_; ++j) s[tid][j] *= inv;
    }
    __syncthreads();

    {   // ctx: 8 d's per thread
        int d0 = (tid & 7) * 8;
        float o[8] = {0,0,0,0,0,0,0,0};
#pragma unroll
        for (int j = 0; j < W_; ++j) {
            float a = s[i][j];
#pragma unroll
            for (int dd = 0; dd < 8; ++dd) o[dd] += a * v[j][d0 + dd];
        }
        float* dst = ctx + (size_t)(n*W_ + i) * D_ + h*DH_ + d0;
#pragma unroll
        for (int dd = 0; dd < 8; ++dd) dst[dd] = o[dd];
    }
}

// ---------------------------------------------------------------------------
// LayerNorm over D=512, IN PLACE: one wave per token (4 waves / block).
// Each lane reads its 8 elements into registers before writing them back.
// ---------------------------------------------------------------------------
__global__ __launch_bounds__(256) void ln_kernel(
    float* x,
    const float* __restrict__ g,
    const float* __restrict__ b)
{
    const int wave  = threadIdx.x >> 6;
    const int lane  = threadIdx.x & 63;
    const int token = blockIdx.x * 4 + wave;
    float* row = x + (size_t)token * D_;
    float vals[8];
    float sum = 0.f, sq = 0.f;
#pragma unroll
    for (int j = 0; j < 8; ++j) {
        float t = row[lane + j*64];
        vals[j] = t; sum += t; sq += t*t;
    }
#pragma unroll
    for (int off = 32; off > 0; off >>= 1) {
        sum += __shfl_down(sum, off);
        sq  += __shfl_down(sq,  off);
    }
    sum = __shfl(sum, 0);
    sq  = __shfl(sq, 0);
    const float mu  = sum * (1.f / D_);
    float var = sq * (1.f / D_) - mu * mu;
    if (var < 0.f) var = 0.f;
    const float rs  = rsqrtf(var + 1e-5f);
#pragma unroll
    for (int j = 0; j < 8; ++j) {
        int d = lane + j*64;
        row[d] = (vals[j] - mu) * rs * g[d] + b[d];
    }
}

// ---------------------------------------------------------------------------
// Head: token = x[n*32+31, :]; logits (NWIN,6) then values (NWIN)
// ---------------------------------------------------------------------------
__global__ __launch_bounds__(64) void head_kernel(
    const float* __restrict__ x,
    const float* __restrict__ Wp, const float* __restrict__ bp,
    const float* __restrict__ Wv, const float* __restrict__ bv,
    float* __restrict__ out)
{
    const int n    = blockIdx.x;
    const int lane = threadIdx.x;
    const float* row = x + (size_t)(n*W_ + (W_-1)) * D_;
    float t[8];
#pragma unroll
    for (int j = 0; j < 8; ++j) t[j] = row[lane + j*64];

    for (int a = 0; a < A_ + 1; ++a) {
        const float* w = (a < A_) ? (Wp + (size_t)a * D_) : Wv;
        float d = 0.f;
#pragma unroll
        for (int j = 0; j < 8; ++j) d += t[j] * w[lane + j*64];
#pragma unroll
        for (int off = 32; off > 0; off >>= 1) d += __shfl_down(d, off);
        if (lane == 0) {
            if (a < A_) out[(size_t)n*A_ + a] = d + bp[a];
            else        out[(size_t)NWIN*A_ + n] = d + bv[0];
        }
    }
}

// ---------------------------------------------------------------------------
extern "C" void kernel_launch(void* const* d_in, const int* in_sizes, int n_in,
                              void* d_out, int out_size, void* d_ws, size_t ws_size,
                              hipStream_t stream) {
    const float* feats = (const float*)d_in[0];
    const float* pos   = (const float*)d_in[1];
    const float* Wqkv  = (const float*)d_in[2];
    const float* bqkv  = (const float*)d_in[3];
    const float* Wo    = (const float*)d_in[4];
    const float* bo    = (const float*)d_in[5];
    const float* ln1g  = (const float*)d_in[6];
    const float* ln1b  = (const float*)d_in[7];
    const float* W1    = (const float*)d_in[8];
    const float* b1    = (const float*)d_in[9];
    const float* W2    = (const float*)d_in[10];
    const float* b2    = (const float*)d_in[11];
    const float* ln2g  = (const float*)d_in[12];
    const float* ln2b  = (const float*)d_in[13];
    const float* Wp    = (const float*)d_in[14];
    const float* bp    = (const float*)d_in[15];
    const float* Wv    = (const float*)d_in[16];
    const float* bv    = (const float*)d_in[17];
    float* out = (float*)d_out;

    // ---- memory plan ----------------------------------------------------
    // persistent: x (NTOK*D fp32) = 128 MiB (in-place residual+LN updates)
    // scratch   : NC*32*2048 fp32 (qkv 1536 + ctx 512 cols in attn phase;
    //             hidden 2048 cols in FFN phase). NC in [4,256].
    // Fits in d_ws if ws_size >= 129 MiB; else dlopen-time fallback buffer.
    int NC = 256;
    while (NC > 4 && X_BYTES + (size_t)NC * SCR_BYTES_PER_NC > ws_size) NC >>= 1;
    float* basep;
    if (X_BYTES + (size_t)NC * SCR_BYTES_PER_NC <= ws_size) {
        basep = (float*)d_ws;
    } else {
        basep = g_fallback;   // sized for NC=256
        NC = 256;
    }
    const int NCHUNK = NWIN / NC;
    const int MC = NC * 32;                        // rows per chunk (mult of 128)
    float* x     = basep;
    float* scr   = x + (size_t)NTOK * D_;
    float* qkv_s = scr;                            // (MC,1536)
    float* ctx_s = scr + (size_t)MC * (3 * D_);    // (MC,512)

    build_x_kernel<<<NTOK * (D_/4) / 256, 256, 0, stream>>>(feats, pos, x);

    for (int i = 0; i < L_; ++i) {
        const float* Wqkv_i = Wqkv + (size_t)i * 3*D_*D_;
        const float* bqkv_i = bqkv + (size_t)i * 3*D_;
        const float* Wo_i   = Wo   + (size_t)i * D_*D_;
        const float* bo_i   = bo   + (size_t)i * D_;
        const float* W1_i   = W1   + (size_t)i * 4*D_*D_;
        const float* b1_i   = b1   + (size_t)i * 4*D_;
        const float* W2_i   = W2   + (size_t)i * D_*4*D_;
        const float* b2_i   = b2   + (size_t)i * D_;

        // ---- attention phase, chunked over windows ----
        for (int c = 0; c < NCHUNK; ++c) {
            const size_t base = (size_t)c * MC;          // token row offset
            // qkv = x[base:] @ Wqkv^T + bqkv
            gemm_kernel<false,false><<<dim3(3*D_/64, MC/128), 256, 0, stream>>>(
                x + base * D_, Wqkv_i, bqkv_i, nullptr, qkv_s, MC, 3*D_, D_);
            // attention -> ctx
            attn_kernel<<<dim3(NC, H_), 256, 0, stream>>>(qkv_s, ctx_s);
            // x[base:] += ctx @ Wo^T + bo   (in place)
            gemm_kernel<false,true><<<dim3(D_/64, MC/128), 256, 0, stream>>>(
                ctx_s, Wo_i, bo_i, x + base * D_, x + base * D_, MC, D_, D_);
        }
        // x = LN1(x) in place
        ln_kernel<<<NTOK/4, 256, 0, stream>>>(x, ln1g + (size_t)i*D_, ln1b + (size_t)i*D_);

        // ---- FFN phase, chunked over windows ----
        for (int c = 0; c < NCHUNK; ++c) {
            const size_t base = (size_t)c * MC;
            // h = relu(x[base:] @ W1^T + b1)   (scr as (MC,2048))
            gemm_kernel<true,false><<<dim3(4*D_/64, MC/128), 256, 0, stream>>>(
                x + base * D_, W1_i, b1_i, nullptr, scr, MC, 4*D_, D_);
            // x[base:] += h @ W2^T + b2   (in place)
            gemm_kernel<false,true><<<dim3(D_/64, MC/128), 256, 0, stream>>>(
                scr, W2_i, b2_i, x + base * D_, x + base * D_, MC, D_, 4*D_);
        }
        // x = LN2(x) in place
        ln_kernel<<<NTOK/4, 256, 0, stream>>>(x, ln2g + (size_t)i*D_, ln2b + (size_t)i*D_);
    }

    head_kernel<<<NWIN, 64, 0, stream>>>(x, Wp, bp, Wv, bv, out);
}

// Round 4
// 7200.788 us; speedup vs baseline: 3.4544x; 3.4544x over previous
//
#include <hip/hip_runtime.h>
#include <hip/hip_bf16.h>
#include <cstdint>
#include <cstddef>

// Problem constants (fixed by reference)
#define B_    8
#define T_    256
#define D_    512
#define W_    32
#define L_    4
#define A_    6
#define H_    8
#define DH_   64
#define NWIN  (B_*T_)        // 2048 windows
#define NTOK  (NWIN*W_)      // 65536 token rows

typedef __hip_bfloat16 bf16;
using bf16x8 = __attribute__((ext_vector_type(8))) short;  // MFMA A/B frag (4 VGPR)
using f32x4  = __attribute__((ext_vector_type(4))) float;  // MFMA C/D frag

// ---- memory plan (bytes) --------------------------------------------------
#define X_BYTES   ((size_t)NTOK * D_ * 4)     // 128 MiB fp32 residual master
#define XB_BYTES  ((size_t)NTOK * D_ * 2)     //  64 MiB bf16 copy for GEMM A
#define WQ_ELEMS  ((size_t)L_ * 3*D_*D_)
#define WO_ELEMS  ((size_t)L_ * D_*D_)
#define W1_ELEMS  ((size_t)L_ * 4*D_*D_)
#define W2_ELEMS  ((size_t)L_ * 4*D_*D_)
#define WB_BYTES  ((WQ_ELEMS + WO_ELEMS + W1_ELEMS + W2_ELEMS) * 2)   // ~25 MiB
#define SCR_BYTES_PER_NC ((size_t)W_ * 2048 * 2)   // 128 KiB/window (bf16)

static char* g_fallback = nullptr;
__attribute__((constructor)) static void alloc_fallback() {
    (void)hipMalloc((void**)&g_fallback,
                    X_BYTES + XB_BYTES + WB_BYTES + 256 * SCR_BYTES_PER_NC);
}

// ---- async global->LDS (16B per lane; LDS dest = wave base + lane*16) -----
typedef __attribute__((address_space(3))) uint8_t* as3p;
typedef const __attribute__((address_space(1))) uint8_t* as1p;
__device__ __forceinline__ void gload_lds16(const void* g, void* l) {
    __builtin_amdgcn_global_load_lds((as1p)(const uint8_t*)g,
                                     (as3p)(uint32_t)(uintptr_t)l, 16, 0, 0);
}

__device__ __forceinline__ float bf2f(short s) {
    return __uint_as_float(((uint32_t)(uint16_t)s) << 16);
}

// ---------------------------------------------------------------------------
// weight convert fp32 -> bf16 (4 elems/thread)
// ---------------------------------------------------------------------------
__global__ __launch_bounds__(256) void cvt_kernel(
    const float* __restrict__ w, bf16* __restrict__ o, int n4)
{
    int i = blockIdx.x * 256 + threadIdx.x;
    if (i >= n4) return;
    float4 f = ((const float4*)w)[i];
    bf16* d = o + (size_t)i * 4;
    d[0] = __float2bfloat16(f.x);
    d[1] = __float2bfloat16(f.y);
    d[2] = __float2bfloat16(f.z);
    d[3] = __float2bfloat16(f.w);
}

// ---------------------------------------------------------------------------
// build_x: x[n*32+w,:] = feats[b, max(t+w-31,0),:] + pos[w,:]; also bf16 copy
// ---------------------------------------------------------------------------
__global__ __launch_bounds__(256) void build_x_kernel(
    const float* __restrict__ feats,
    const float* __restrict__ pos,
    float* __restrict__ x,
    bf16* __restrict__ xb)
{
    int gid   = blockIdx.x * 256 + threadIdx.x;   // over NTOK * (D/4)
    int token = gid >> 7;
    int c4    = (gid & 127) * 4;
    int w     = token & (W_-1);
    int n     = token >> 5;
    int t     = n & (T_-1);
    int b     = n >> 8;
    int frame = t + w - (W_-1); if (frame < 0) frame = 0;
    const float4 f = *(const float4*)(feats + ((size_t)(b*T_ + frame)*D_ + c4));
    const float4 p = *(const float4*)(pos   + ((size_t)w*D_ + c4));
    float4 r; r.x = f.x+p.x; r.y = f.y+p.y; r.z = f.z+p.z; r.w = f.w+p.w;
    *(float4*)(x + (size_t)token*D_ + c4) = r;
    bf16* d = xb + (size_t)token*D_ + c4;
    d[0] = __float2bfloat16(r.x);
    d[1] = __float2bfloat16(r.y);
    d[2] = __float2bfloat16(r.z);
    d[3] = __float2bfloat16(r.w);
}

// ---------------------------------------------------------------------------
// bf16 MFMA GEMM (m97 structure): C = A(MxK) @ Bt(NxK)^T + bias [+resid][relu]
// 128x128 tile, BK=32, 256 thr = 4 waves, each wave 64x64 (4x4 16x16x32 MFMA).
// OUTBF: write bf16 Cb; else fp32 C32 (resid may alias C32 - same thread rw).
// M%128==0, N%128==0, K%32==0.
// ---------------------------------------------------------------------------
template<bool RELU, bool RESID, bool OUTBF>
__global__ __launch_bounds__(256) void gemm_mfma(
    const bf16* __restrict__ A,
    const bf16* __restrict__ Bt,
    const float* __restrict__ bias,
    const float* resid,
    float* C32,
    bf16* Cb,
    int M, int N, int K)
{
    __shared__ bf16 As[128*32];   // [row][k] row-major, 64B rows
    __shared__ bf16 Bs[128*32];

    const int tid  = threadIdx.x;
    const int lane = tid & 63;
    const int wv   = tid >> 6;
    const int m0   = blockIdx.y * 128;
    const int n0   = blockIdx.x * 128;
    const int wm   = (wv >> 1) * 64;   // wave row offset in tile
    const int wn   = (wv & 1) * 64;    // wave col offset in tile

    f32x4 acc[4][4] = {};

    // staging: wave wv stages 16 rows per half; lane -> row lane>>2, 16B chunk lane&3
    const int   srow  = wv*16 + (lane >> 2);
    const int   skoff = (lane & 3) * 8;          // elements
    const bf16* ga0 = A  + (size_t)(m0 + srow)      * K + skoff;
    const bf16* ga1 = A  + (size_t)(m0 + 64 + srow) * K + skoff;
    const bf16* gb0 = Bt + (size_t)(n0 + srow)      * K + skoff;
    const bf16* gb1 = Bt + (size_t)(n0 + 64 + srow) * K + skoff;
    char* lAs = (char*)As;
    char* lBs = (char*)Bs;
    const int l0 = wv*1024 + lane*16;            // == srow*64 + (lane&3)*16

    const int fr = lane & 15;                    // fragment row (m or n)
    const int fq = (lane >> 4) * 16;             // 16B k-chunk

    for (int k0 = 0; k0 < K; k0 += 32) {
        gload_lds16(ga0 + k0, lAs + l0);
        gload_lds16(ga1 + k0, lAs + l0 + 4096);
        gload_lds16(gb0 + k0, lBs + l0);
        gload_lds16(gb1 + k0, lBs + l0 + 4096);
        __syncthreads();   // drains vmcnt (DMA) before reads

        bf16x8 av[4], bv[4];
#pragma unroll
        for (int i = 0; i < 4; ++i) {
            av[i] = *(const bf16x8*)(lAs + (wm + i*16 + fr)*64 + fq);
            bv[i] = *(const bf16x8*)(lBs + (wn + i*16 + fr)*64 + fq);
        }
#pragma unroll
        for (int i = 0; i < 4; ++i)
#pragma unroll
            for (int j = 0; j < 4; ++j)
                acc[i][j] = __builtin_amdgcn_mfma_f32_16x16x32_bf16(
                    av[i], bv[j], acc[i][j], 0, 0, 0);
        __syncthreads();   // all waves done reading before next DMA
    }

    // epilogue: C/D layout col=lane&15, row=(lane>>4)*4+reg  [m89/m91 verified]
    const int er = (lane >> 4) * 4;
    const int ec = lane & 15;
#pragma unroll
    for (int i = 0; i < 4; ++i) {
#pragma unroll
        for (int j = 0; j < 4; ++j) {
            const int ncol = n0 + wn + j*16 + ec;
            const float bv_ = bias[ncol];
#pragma unroll
            for (int r = 0; r < 4; ++r) {
                const int mrow = m0 + wm + i*16 + er + r;
                float v = acc[i][j][r] + bv_;
                if (RESID) v += resid[(size_t)mrow * N + ncol];
                if (RELU)  v = fmaxf(v, 0.f);
                if (OUTBF) Cb[(size_t)mrow * N + ncol] = __float2bfloat16(v);
                else       C32[(size_t)mrow * N + ncol] = v;
            }
        }
    }
}

// ---------------------------------------------------------------------------
// Attention: block per (window, head); bf16 qkv in, bf16 ctx out; fp32 inside.
// ---------------------------------------------------------------------------
__global__ __launch_bounds__(256) void attn_kernel(
    const bf16* __restrict__ qkv,
    bf16* __restrict__ ctx)
{
    const int n = blockIdx.x;
    const int h = blockIdx.y;
    __shared__ float q[W_][DH_];
    __shared__ float k[W_][DH_];
    __shared__ float v[W_][DH_];
    __shared__ float s[W_][W_ + 1];

    const int tid = threadIdx.x;
    {   // load q,k,v: row tid>>3, 8 cols via 16B bf16 loads
        int r  = tid >> 3;
        int c0 = (tid & 7) * 8;
        const bf16* base = qkv + (size_t)(n*W_ + r) * (3*D_) + h*DH_ + c0;
        bf16x8 tq = *(const bf16x8*)(base);
        bf16x8 tk = *(const bf16x8*)(base + D_);
        bf16x8 tv = *(const bf16x8*)(base + 2*D_);
#pragma unroll
        for (int j = 0; j < 8; ++j) {
            q[r][c0 + j] = bf2f(tq[j]);
            k[r][c0 + j] = bf2f(tk[j]);
            v[r][c0 + j] = bf2f(tv[j]);
        }
    }
    __syncthreads();

    const int i = tid >> 3;
    {   // scores
        int j0 = (tid & 7) * 4;
#pragma unroll
        for (int jj = 0; jj < 4; ++jj) {
            int j = j0 + jj;
            float d = 0.f;
#pragma unroll
            for (int kk = 0; kk < DH_; ++kk) d += q[i][kk] * k[j][kk];
            s[i][j] = (j <= i) ? d * 0.125f : -1e30f;
        }
    }
    __syncthreads();

    if (tid < W_) {   // softmax row
        float mx = -1e30f;
#pragma unroll
        for (int j = 0; j < W_; ++j) mx = fmaxf(mx, s[tid][j]);
        float sum = 0.f;
#pragma unroll
        for (int j = 0; j < W_; ++j) { float e = __expf(s[tid][j] - mx); s[tid][j] = e; sum += e; }
        float inv = 1.f / sum;
#pragma unroll
        for (int j = 0; j < W_; ++j) s[tid][j] *= inv;
    }
    __syncthreads();

    {   // ctx
        int d0 = (tid & 7) * 8;
        float o[8] = {0,0,0,0,0,0,0,0};
#pragma unroll
        for (int j = 0; j < W_; ++j) {
            float a = s[i][j];
#pragma unroll
            for (int dd = 0; dd < 8; ++dd) o[dd] += a * v[j][d0 + dd];
        }
        bf16* dst = ctx + (size_t)(n*W_ + i) * D_ + h*DH_ + d0;
#pragma unroll
        for (int dd = 0; dd < 8; ++dd) dst[dd] = __float2bfloat16(o[dd]);
    }
}

// ---------------------------------------------------------------------------
// LayerNorm in place on fp32 x; also writes bf16 copy. One wave per token.
// ---------------------------------------------------------------------------
__global__ __launch_bounds__(256) void ln_kernel(
    float* x, bf16* __restrict__ xb,
    const float* __restrict__ g,
    const float* __restrict__ b)
{
    const int wave  = threadIdx.x >> 6;
    const int lane  = threadIdx.x & 63;
    const int token = blockIdx.x * 4 + wave;
    float* row  = x  + (size_t)token * D_;
    bf16*  rowb = xb + (size_t)token * D_;
    float vals[8];
    float sum = 0.f, sq = 0.f;
#pragma unroll
    for (int j = 0; j < 8; ++j) {
        float t = row[lane + j*64];
        vals[j] = t; sum += t; sq += t*t;
    }
#pragma unroll
    for (int off = 32; off > 0; off >>= 1) {
        sum += __shfl_down(sum, off);
        sq  += __shfl_down(sq,  off);
    }
    sum = __shfl(sum, 0);
    sq  = __shfl(sq, 0);
    const float mu = sum * (1.f / D_);
    float var = sq * (1.f / D_) - mu * mu;
    if (var < 0.f) var = 0.f;
    const float rs = rsqrtf(var + 1e-5f);
#pragma unroll
    for (int j = 0; j < 8; ++j) {
        int d = lane + j*64;
        float o = (vals[j] - mu) * rs * g[d] + b[d];
        row[d]  = o;
        rowb[d] = __float2bfloat16(o);
    }
}

// ---------------------------------------------------------------------------
// Head: token = x[n*32+31,:] fp32; logits (NWIN,6) then values (NWIN)
// ---------------------------------------------------------------------------
__global__ __launch_bounds__(64) void head_kernel(
    const float* __restrict__ x,
    const float* __restrict__ Wp, const float* __restrict__ bp,
    const float* __restrict__ Wv, const float* __restrict__ bv,
    float* __restrict__ out)
{
    const int n    = blockIdx.x;
    const int lane = threadIdx.x;
    const float* row = x + (size_t)(n*W_ + (W_-1)) * D_;
    float t[8];
#pragma unroll
    for (int j = 0; j < 8; ++j) t[j] = row[lane + j*64];

    for (int a = 0; a < A_ + 1; ++a) {
        const float* w = (a < A_) ? (Wp + (size_t)a * D_) : Wv;
        float d = 0.f;
#pragma unroll
        for (int j = 0; j < 8; ++j) d += t[j] * w[lane + j*64];
#pragma unroll
        for (int off = 32; off > 0; off >>= 1) d += __shfl_down(d, off);
        if (lane == 0) {
            if (a < A_) out[(size_t)n*A_ + a] = d + bp[a];
            else        out[(size_t)NWIN*A_ + n] = d + bv[0];
        }
    }
}

// ---------------------------------------------------------------------------
extern "C" void kernel_launch(void* const* d_in, const int* in_sizes, int n_in,
                              void* d_out, int out_size, void* d_ws, size_t ws_size,
                              hipStream_t stream) {
    const float* feats = (const float*)d_in[0];
    const float* pos   = (const float*)d_in[1];
    const float* Wqkv  = (const float*)d_in[2];
    const float* bqkv  = (const float*)d_in[3];
    const float* Wo    = (const float*)d_in[4];
    const float* bo    = (const float*)d_in[5];
    const float* ln1g  = (const float*)d_in[6];
    const float* ln1b  = (const float*)d_in[7];
    const float* W1    = (const float*)d_in[8];
    const float* b1    = (const float*)d_in[9];
    const float* W2    = (const float*)d_in[10];
    const float* b2    = (const float*)d_in[11];
    const float* ln2g  = (const float*)d_in[12];
    const float* ln2b  = (const float*)d_in[13];
    const float* Wp    = (const float*)d_in[14];
    const float* bp    = (const float*)d_in[15];
    const float* Wv    = (const float*)d_in[16];
    const float* bv    = (const float*)d_in[17];
    float* out = (float*)d_out;

    // ---- workspace carve-out -------------------------------------------
    const size_t FIXED = X_BYTES + XB_BYTES + WB_BYTES;
    int NC = 256;
    while (NC > 4 && FIXED + (size_t)NC * SCR_BYTES_PER_NC > ws_size) NC >>= 1;
    char* basep;
    if (FIXED + (size_t)NC * SCR_BYTES_PER_NC <= ws_size) {
        basep = (char*)d_ws;
    } else {
        basep = g_fallback;   // sized for NC=256
        NC = 256;
    }
    const int NCHUNK = NWIN / NC;
    const int MC = NC * W_;                       // rows per chunk (mult of 128)

    float* x    = (float*)basep;
    bf16*  xb   = (bf16*)(basep + X_BYTES);
    bf16*  wq_b = (bf16*)(basep + X_BYTES + XB_BYTES);
    bf16*  wo_b = wq_b + WQ_ELEMS;
    bf16*  w1_b = wo_b + WO_ELEMS;
    bf16*  w2_b = w1_b + W1_ELEMS;
    bf16*  scr  = w2_b + W2_ELEMS;
    bf16*  qkv_s = scr;                           // (MC, 1536)
    bf16*  ctx_s = scr + (size_t)MC * (3*D_);     // (MC, 512)
    bf16*  h_s   = scr;                           // (MC, 2048) FFN phase

    // convert weights to bf16 (weights restored pristine each call)
    cvt_kernel<<<(WQ_ELEMS/4 + 255)/256, 256, 0, stream>>>(Wqkv, wq_b, WQ_ELEMS/4);
    cvt_kernel<<<(WO_ELEMS/4 + 255)/256, 256, 0, stream>>>(Wo,   wo_b, WO_ELEMS/4);
    cvt_kernel<<<(W1_ELEMS/4 + 255)/256, 256, 0, stream>>>(W1,   w1_b, W1_ELEMS/4);
    cvt_kernel<<<(W2_ELEMS/4 + 255)/256, 256, 0, stream>>>(W2,   w2_b, W2_ELEMS/4);

    build_x_kernel<<<NTOK * (D_/4) / 256, 256, 0, stream>>>(feats, pos, x, xb);

    for (int i = 0; i < L_; ++i) {
        const bf16*  wq_i = wq_b + (size_t)i * 3*D_*D_;
        const float* bq_i = bqkv + (size_t)i * 3*D_;
        const bf16*  wo_i = wo_b + (size_t)i * D_*D_;
        const float* bo_i = bo   + (size_t)i * D_;
        const bf16*  w1_i = w1_b + (size_t)i * 4*D_*D_;
        const float* b1_i = b1   + (size_t)i * 4*D_;
        const bf16*  w2_i = w2_b + (size_t)i * 4*D_*D_;
        const float* b2_i = b2   + (size_t)i * D_;

        // ---- attention phase, chunked ----
        for (int c = 0; c < NCHUNK; ++c) {
            const size_t base = (size_t)c * MC;
            gemm_mfma<false,false,true><<<dim3(3*D_/128, MC/128), 256, 0, stream>>>(
                xb + base*D_, wq_i, bq_i, nullptr, nullptr, qkv_s, MC, 3*D_, D_);
            attn_kernel<<<dim3(NC, H_), 256, 0, stream>>>(qkv_s, ctx_s);
            gemm_mfma<false,true,false><<<dim3(D_/128, MC/128), 256, 0, stream>>>(
                ctx_s, wo_i, bo_i, x + base*D_, x + base*D_, nullptr, MC, D_, D_);
        }
        ln_kernel<<<NTOK/4, 256, 0, stream>>>(x, xb, ln1g + (size_t)i*D_, ln1b + (size_t)i*D_);

        // ---- FFN phase, chunked ----
        for (int c = 0; c < NCHUNK; ++c) {
            const size_t base = (size_t)c * MC;
            gemm_mfma<true,false,true><<<dim3(4*D_/128, MC/128), 256, 0, stream>>>(
                xb + base*D_, w1_i, b1_i, nullptr, nullptr, h_s, MC, 4*D_, D_);
            gemm_mfma<false,true,false><<<dim3(D_/128, MC/128), 256, 0, stream>>>(
                h_s, w2_i, b2_i, x + base*D_, x + base*D_, nullptr, MC, D_, 4*D_);
        }
        ln_kernel<<<NTOK/4, 256, 0, stream>>>(x, xb, ln2g + (size_t)i*D_, ln2b + (size_t)i*D_);
    }

    head_kernel<<<NWIN, 64, 0, stream>>>(x, Wp, bp, Wv, bv, out);
}

// Round 5
// 6146.241 us; speedup vs baseline: 4.0470x; 1.1716x over previous
//
#include <hip/hip_runtime.h>
#include <hip/hip_bf16.h>
#include <cstdint>
#include <cstddef>

// Problem constants (fixed by reference)
#define B_    8
#define T_    256
#define D_    512
#define W_    32
#define L_    4
#define A_    6
#define H_    8
#define DH_   64
#define DHP   65                 // padded LDS row: bank (r*65+c)%32 varies with r
#define NWIN  (B_*T_)            // 2048 windows
#define NTOK  (NWIN*W_)          // 65536 token rows

typedef __hip_bfloat16 bf16;
using bf16x8 = __attribute__((ext_vector_type(8))) short;  // MFMA A/B frag (4 VGPR)
using f32x4  = __attribute__((ext_vector_type(4))) float;  // MFMA C/D frag

// ---- memory plan (bytes) --------------------------------------------------
#define X_BYTES   ((size_t)NTOK * D_ * 4)     // 128 MiB fp32 residual master
#define XB_BYTES  ((size_t)NTOK * D_ * 2)     //  64 MiB bf16 copy for GEMM A
#define WQ_ELEMS  ((size_t)L_ * 3*D_*D_)
#define WO_ELEMS  ((size_t)L_ * D_*D_)
#define W1_ELEMS  ((size_t)L_ * 4*D_*D_)
#define W2_ELEMS  ((size_t)L_ * 4*D_*D_)
#define WB_BYTES  ((WQ_ELEMS + WO_ELEMS + W1_ELEMS + W2_ELEMS) * 2)   // ~25 MiB
#define SCR_BYTES_PER_NC ((size_t)W_ * 2048 * 2)   // 128 KiB/window (bf16)

static char* g_fallback = nullptr;
__attribute__((constructor)) static void alloc_fallback() {
    (void)hipMalloc((void**)&g_fallback,
                    X_BYTES + XB_BYTES + WB_BYTES + 256 * SCR_BYTES_PER_NC);
}

// ---- async global->LDS (16B per lane; LDS dest = wave base + lane*16) -----
typedef __attribute__((address_space(3))) uint8_t* as3p;
typedef const __attribute__((address_space(1))) uint8_t* as1p;
__device__ __forceinline__ void gload_lds16(const void* g, void* l) {
    __builtin_amdgcn_global_load_lds((as1p)(const uint8_t*)g,
                                     (as3p)(uint32_t)(uintptr_t)l, 16, 0, 0);
}

__device__ __forceinline__ float bf2f(short s) {
    return __uint_as_float(((uint32_t)(uint16_t)s) << 16);
}

// ---------------------------------------------------------------------------
// weight convert fp32 -> bf16 (4 elems/thread)
// ---------------------------------------------------------------------------
__global__ __launch_bounds__(256) void cvt_kernel(
    const float* __restrict__ w, bf16* __restrict__ o, int n4)
{
    int i = blockIdx.x * 256 + threadIdx.x;
    if (i >= n4) return;
    float4 f = ((const float4*)w)[i];
    bf16* d = o + (size_t)i * 4;
    d[0] = __float2bfloat16(f.x);
    d[1] = __float2bfloat16(f.y);
    d[2] = __float2bfloat16(f.z);
    d[3] = __float2bfloat16(f.w);
}

// ---------------------------------------------------------------------------
// build_x: x[n*32+w,:] = feats[b, max(t+w-31,0),:] + pos[w,:]; also bf16 copy
// ---------------------------------------------------------------------------
__global__ __launch_bounds__(256) void build_x_kernel(
    const float* __restrict__ feats,
    const float* __restrict__ pos,
    float* __restrict__ x,
    bf16* __restrict__ xb)
{
    int gid   = blockIdx.x * 256 + threadIdx.x;   // over NTOK * (D/4)
    int token = gid >> 7;
    int c4    = (gid & 127) * 4;
    int w     = token & (W_-1);
    int n     = token >> 5;
    int t     = n & (T_-1);
    int b     = n >> 8;
    int frame = t + w - (W_-1); if (frame < 0) frame = 0;
    const float4 f = *(const float4*)(feats + ((size_t)(b*T_ + frame)*D_ + c4));
    const float4 p = *(const float4*)(pos   + ((size_t)w*D_ + c4));
    float4 r; r.x = f.x+p.x; r.y = f.y+p.y; r.z = f.z+p.z; r.w = f.w+p.w;
    *(float4*)(x + (size_t)token*D_ + c4) = r;
    bf16* d = xb + (size_t)token*D_ + c4;
    d[0] = __float2bfloat16(r.x);
    d[1] = __float2bfloat16(r.y);
    d[2] = __float2bfloat16(r.z);
    d[3] = __float2bfloat16(r.w);
}

// ---------------------------------------------------------------------------
// bf16 MFMA GEMM (m97 structure): C = A(MxK) @ Bt(NxK)^T + bias [+resid][relu]
// 128x128 tile, BK=32, 256 thr = 4 waves, each wave 64x64 (4x4 16x16x32 MFMA).
// OUTBF: write bf16 Cb; else fp32 C32 (resid may alias C32 - same thread rw).
// M%128==0, N%128==0, K%32==0.
// ---------------------------------------------------------------------------
template<bool RELU, bool RESID, bool OUTBF>
__global__ __launch_bounds__(256) void gemm_mfma(
    const bf16* __restrict__ A,
    const bf16* __restrict__ Bt,
    const float* __restrict__ bias,
    const float* resid,
    float* C32,
    bf16* Cb,
    int M, int N, int K)
{
    __shared__ bf16 As[128*32];   // [row][k] row-major, 64B rows
    __shared__ bf16 Bs[128*32];

    const int tid  = threadIdx.x;
    const int lane = tid & 63;
    const int wv   = tid >> 6;
    const int m0   = blockIdx.y * 128;
    const int n0   = blockIdx.x * 128;
    const int wm   = (wv >> 1) * 64;   // wave row offset in tile
    const int wn   = (wv & 1) * 64;    // wave col offset in tile

    f32x4 acc[4][4] = {};

    // staging: wave wv stages 16 rows per half; lane -> row lane>>2, 16B chunk lane&3
    const int   srow  = wv*16 + (lane >> 2);
    const int   skoff = (lane & 3) * 8;          // elements
    const bf16* ga0 = A  + (size_t)(m0 + srow)      * K + skoff;
    const bf16* ga1 = A  + (size_t)(m0 + 64 + srow) * K + skoff;
    const bf16* gb0 = Bt + (size_t)(n0 + srow)      * K + skoff;
    const bf16* gb1 = Bt + (size_t)(n0 + 64 + srow) * K + skoff;
    char* lAs = (char*)As;
    char* lBs = (char*)Bs;
    const int l0 = wv*1024 + lane*16;            // == srow*64 + (lane&3)*16

    const int fr = lane & 15;                    // fragment row (m or n)
    const int fq = (lane >> 4) * 16;             // 16B k-chunk

    for (int k0 = 0; k0 < K; k0 += 32) {
        gload_lds16(ga0 + k0, lAs + l0);
        gload_lds16(ga1 + k0, lAs + l0 + 4096);
        gload_lds16(gb0 + k0, lBs + l0);
        gload_lds16(gb1 + k0, lBs + l0 + 4096);
        __syncthreads();   // drains vmcnt (DMA) before reads

        bf16x8 av[4], bv[4];
#pragma unroll
        for (int i = 0; i < 4; ++i) {
            av[i] = *(const bf16x8*)(lAs + (wm + i*16 + fr)*64 + fq);
            bv[i] = *(const bf16x8*)(lBs + (wn + i*16 + fr)*64 + fq);
        }
#pragma unroll
        for (int i = 0; i < 4; ++i)
#pragma unroll
            for (int j = 0; j < 4; ++j)
                acc[i][j] = __builtin_amdgcn_mfma_f32_16x16x32_bf16(
                    av[i], bv[j], acc[i][j], 0, 0, 0);
        __syncthreads();   // all waves done reading before next DMA
    }

    // epilogue: C/D layout col=lane&15, row=(lane>>4)*4+reg  [m89/m91 verified]
    const int er = (lane >> 4) * 4;
    const int ec = lane & 15;
#pragma unroll
    for (int i = 0; i < 4; ++i) {
#pragma unroll
        for (int j = 0; j < 4; ++j) {
            const int ncol = n0 + wn + j*16 + ec;
            const float bv_ = bias[ncol];
#pragma unroll
            for (int r = 0; r < 4; ++r) {
                const int mrow = m0 + wm + i*16 + er + r;
                float v = acc[i][j][r] + bv_;
                if (RESID) v += resid[(size_t)mrow * N + ncol];
                if (RELU)  v = fmaxf(v, 0.f);
                if (OUTBF) Cb[(size_t)mrow * N + ncol] = __float2bfloat16(v);
                else       C32[(size_t)mrow * N + ncol] = v;
            }
        }
    }
}

// ---------------------------------------------------------------------------
// Attention: block per (window, head); bf16 qkv in, bf16 ctx out; fp32 inside.
// LDS rows padded to DHP=65 floats: score-loop k[j][kk] banks = (j+kk)%32,
// distinct across the wave's 8 row-addresses (was 8-way same-bank at stride 64
// -> 2.8e7 SQ_LDS_BANK_CONFLICT/dispatch in R4).
// ---------------------------------------------------------------------------
__global__ __launch_bounds__(256) void attn_kernel(
    const bf16* __restrict__ qkv,
    bf16* __restrict__ ctx)
{
    const int n = blockIdx.x;
    const int h = blockIdx.y;
    __shared__ float q[W_][DHP];
    __shared__ float k[W_][DHP];
    __shared__ float v[W_][DHP];
    __shared__ float s[W_][W_ + 1];

    const int tid = threadIdx.x;
    {   // load q,k,v: row tid>>3, 8 cols via 16B bf16 loads
        int r  = tid >> 3;
        int c0 = (tid & 7) * 8;
        const bf16* base = qkv + (size_t)(n*W_ + r) * (3*D_) + h*DH_ + c0;
        bf16x8 tq = *(const bf16x8*)(base);
        bf16x8 tk = *(const bf16x8*)(base + D_);
        bf16x8 tv = *(const bf16x8*)(base + 2*D_);
#pragma unroll
        for (int j = 0; j < 8; ++j) {
            q[r][c0 + j] = bf2f(tq[j]);
            k[r][c0 + j] = bf2f(tk[j]);
            v[r][c0 + j] = bf2f(tv[j]);
        }
    }
    __syncthreads();

    const int i = tid >> 3;
    {   // scores
        int j0 = (tid & 7) * 4;
#pragma unroll
        for (int jj = 0; jj < 4; ++jj) {
            int j = j0 + jj;
            float d = 0.f;
#pragma unroll
            for (int kk = 0; kk < DH_; ++kk) d += q[i][kk] * k[j][kk];
            s[i][j] = (j <= i) ? d * 0.125f : -1e30f;
        }
    }
    __syncthreads();

    if (tid < W_) {   // softmax row
        float mx = -1e30f;
#pragma unroll
        for (int j = 0; j < W_; ++j) mx = fmaxf(mx, s[tid][j]);
        float sum = 0.f;
#pragma unroll
        for (int j = 0; j < W_; ++j) { float e = __expf(s[tid][j] - mx); s[tid][j] = e; sum += e; }
        float inv = 1.f / sum;
#pragma unroll
        for (int j = 0; j < W_; ++j) s[tid][j] *= inv;
    }
    __syncthreads();

    {   // ctx
        int d0 = (tid & 7) * 8;
        float o[8] = {0,0,0,0,0,0,0,0};
#pragma unroll
        for (int j = 0; j < W_; ++j) {
            float a = s[i][j];
#pragma unroll
            for (int dd = 0; dd < 8; ++dd) o[dd] += a * v[j][d0 + dd];
        }
        bf16* dst = ctx + (size_t)(n*W_ + i) * D_ + h*DH_ + d0;
#pragma unroll
        for (int dd = 0; dd < 8; ++dd) dst[dd] = __float2bfloat16(o[dd]);
    }
}

// ---------------------------------------------------------------------------
// LayerNorm in place on fp32 x; also writes bf16 copy. One wave per token.
// ---------------------------------------------------------------------------
__global__ __launch_bounds__(256) void ln_kernel(
    float* x, bf16* __restrict__ xb,
    const float* __restrict__ g,
    const float* __restrict__ b)
{
    const int wave  = threadIdx.x >> 6;
    const int lane  = threadIdx.x & 63;
    const int token = blockIdx.x * 4 + wave;
    float* row  = x  + (size_t)token * D_;
    bf16*  rowb = xb + (size_t)token * D_;
    float vals[8];
    float sum = 0.f, sq = 0.f;
#pragma unroll
    for (int j = 0; j < 8; ++j) {
        float t = row[lane + j*64];
        vals[j] = t; sum += t; sq += t*t;
    }
#pragma unroll
    for (int off = 32; off > 0; off >>= 1) {
        sum += __shfl_down(sum, off);
        sq  += __shfl_down(sq,  off);
    }
    sum = __shfl(sum, 0);
    sq  = __shfl(sq, 0);
    const float mu = sum * (1.f / D_);
    float var = sq * (1.f / D_) - mu * mu;
    if (var < 0.f) var = 0.f;
    const float rs = rsqrtf(var + 1e-5f);
#pragma unroll
    for (int j = 0; j < 8; ++j) {
        int d = lane + j*64;
        float o = (vals[j] - mu) * rs * g[d] + b[d];
        row[d]  = o;
        rowb[d] = __float2bfloat16(o);
    }
}

// ---------------------------------------------------------------------------
// Head: token = x[n*32+31,:] fp32; logits (NWIN,6) then values (NWIN)
// ---------------------------------------------------------------------------
__global__ __launch_bounds__(64) void head_kernel(
    const float* __restrict__ x,
    const float* __restrict__ Wp, const float* __restrict__ bp,
    const float* __restrict__ Wv, const float* __restrict__ bv,
    float* __restrict__ out)
{
    const int n    = blockIdx.x;
    const int lane = threadIdx.x;
    const float* row = x + (size_t)(n*W_ + (W_-1)) * D_;
    float t[8];
#pragma unroll
    for (int j = 0; j < 8; ++j) t[j] = row[lane + j*64];

    for (int a = 0; a < A_ + 1; ++a) {
        const float* w = (a < A_) ? (Wp + (size_t)a * D_) : Wv;
        float d = 0.f;
#pragma unroll
        for (int j = 0; j < 8; ++j) d += t[j] * w[lane + j*64];
#pragma unroll
        for (int off = 32; off > 0; off >>= 1) d += __shfl_down(d, off);
        if (lane == 0) {
            if (a < A_) out[(size_t)n*A_ + a] = d + bp[a];
            else        out[(size_t)NWIN*A_ + n] = d + bv[0];
        }
    }
}

// ---------------------------------------------------------------------------
extern "C" void kernel_launch(void* const* d_in, const int* in_sizes, int n_in,
                              void* d_out, int out_size, void* d_ws, size_t ws_size,
                              hipStream_t stream) {
    const float* feats = (const float*)d_in[0];
    const float* pos   = (const float*)d_in[1];
    const float* Wqkv  = (const float*)d_in[2];
    const float* bqkv  = (const float*)d_in[3];
    const float* Wo    = (const float*)d_in[4];
    const float* bo    = (const float*)d_in[5];
    const float* ln1g  = (const float*)d_in[6];
    const float* ln1b  = (const float*)d_in[7];
    const float* W1    = (const float*)d_in[8];
    const float* b1    = (const float*)d_in[9];
    const float* W2    = (const float*)d_in[10];
    const float* b2    = (const float*)d_in[11];
    const float* ln2g  = (const float*)d_in[12];
    const float* ln2b  = (const float*)d_in[13];
    const float* Wp    = (const float*)d_in[14];
    const float* bp    = (const float*)d_in[15];
    const float* Wv    = (const float*)d_in[16];
    const float* bv    = (const float*)d_in[17];
    float* out = (float*)d_out;

    // ---- workspace carve-out -------------------------------------------
    // NC up to 1024 (fewer dispatches) when ws allows; fallback sized for 256.
    const size_t FIXED = X_BYTES + XB_BYTES + WB_BYTES;
    int NC = 1024;
    while (NC > 4 && FIXED + (size_t)NC * SCR_BYTES_PER_NC > ws_size) NC >>= 1;
    char* basep;
    if (FIXED + (size_t)NC * SCR_BYTES_PER_NC <= ws_size) {
        basep = (char*)d_ws;
    } else {
        basep = g_fallback;   // sized for NC=256
        NC = 256;
    }
    const int NCHUNK = NWIN / NC;
    const int MC = NC * W_;                       // rows per chunk (mult of 128)

    float* x    = (float*)basep;
    bf16*  xb   = (bf16*)(basep + X_BYTES);
    bf16*  wq_b = (bf16*)(basep + X_BYTES + XB_BYTES);
    bf16*  wo_b = wq_b + WQ_ELEMS;
    bf16*  w1_b = wo_b + WO_ELEMS;
    bf16*  w2_b = w1_b + W1_ELEMS;
    bf16*  scr  = w2_b + W2_ELEMS;
    bf16*  qkv_s = scr;                           // (MC, 1536)
    bf16*  ctx_s = scr + (size_t)MC * (3*D_);     // (MC, 512)
    bf16*  h_s   = scr;                           // (MC, 2048) FFN phase

    // convert weights to bf16 (weights restored pristine each call)
    cvt_kernel<<<(WQ_ELEMS/4 + 255)/256, 256, 0, stream>>>(Wqkv, wq_b, WQ_ELEMS/4);
    cvt_kernel<<<(WO_ELEMS/4 + 255)/256, 256, 0, stream>>>(Wo,   wo_b, WO_ELEMS/4);
    cvt_kernel<<<(W1_ELEMS/4 + 255)/256, 256, 0, stream>>>(W1,   w1_b, W1_ELEMS/4);
    cvt_kernel<<<(W2_ELEMS/4 + 255)/256, 256, 0, stream>>>(W2,   w2_b, W2_ELEMS/4);

    build_x_kernel<<<NTOK * (D_/4) / 256, 256, 0, stream>>>(feats, pos, x, xb);

    for (int i = 0; i < L_; ++i) {
        const bf16*  wq_i = wq_b + (size_t)i * 3*D_*D_;
        const float* bq_i = bqkv + (size_t)i * 3*D_;
        const bf16*  wo_i = wo_b + (size_t)i * D_*D_;
        const float* bo_i = bo   + (size_t)i * D_;
        const bf16*  w1_i = w1_b + (size_t)i * 4*D_*D_;
        const float* b1_i = b1   + (size_t)i * 4*D_;
        const bf16*  w2_i = w2_b + (size_t)i * 4*D_*D_;
        const float* b2_i = b2   + (size_t)i * D_;

        // ---- attention phase, chunked ----
        for (int c = 0; c < NCHUNK; ++c) {
            const size_t base = (size_t)c * MC;
            gemm_mfma<false,false,true><<<dim3(3*D_/128, MC/128), 256, 0, stream>>>(
                xb + base*D_, wq_i, bq_i, nullptr, nullptr, qkv_s, MC, 3*D_, D_);
            attn_kernel<<<dim3(NC, H_), 256, 0, stream>>>(qkv_s, ctx_s);
            gemm_mfma<false,true,false><<<dim3(D_/128, MC/128), 256, 0, stream>>>(
                ctx_s, wo_i, bo_i, x + base*D_, x + base*D_, nullptr, MC, D_, D_);
        }
        ln_kernel<<<NTOK/4, 256, 0, stream>>>(x, xb, ln1g + (size_t)i*D_, ln1b + (size_t)i*D_);

        // ---- FFN phase, chunked ----
        for (int c = 0; c < NCHUNK; ++c) {
            const size_t base = (size_t)c * MC;
            gemm_mfma<true,false,true><<<dim3(4*D_/128, MC/128), 256, 0, stream>>>(
                xb + base*D_, w1_i, b1_i, nullptr, nullptr, h_s, MC, 4*D_, D_);
            gemm_mfma<false,true,false><<<dim3(D_/128, MC/128), 256, 0, stream>>>(
                h_s, w2_i, b2_i, x + base*D_, x + base*D_, nullptr, MC, D_, 4*D_);
        }
        ln_kernel<<<NTOK/4, 256, 0, stream>>>(x, xb, ln2g + (size_t)i*D_, ln2b + (size_t)i*D_);
    }

    head_kernel<<<NWIN, 64, 0, stream>>>(x, Wp, bp, Wv, bv, out);
}

// Round 6
// 4890.404 us; speedup vs baseline: 5.0863x; 1.2568x over previous
//
#include <hip/hip_runtime.h>
#include <hip/hip_bf16.h>
#include <cstdint>
#include <cstddef>

// Problem constants (fixed by reference)
#define B_    8
#define T_    256
#define D_    512
#define W_    32
#define L_    4
#define A_    6
#define H_    8
#define DH_   64
#define DHP   65                 // padded LDS row: bank (r*65+c)%32 varies with r
#define NWIN  (B_*T_)            // 2048 windows
#define NTOK  (NWIN*W_)          // 65536 token rows

typedef __hip_bfloat16 bf16;
using bf16x8 = __attribute__((ext_vector_type(8))) short;  // MFMA A/B frag (4 VGPR)
using f32x4  = __attribute__((ext_vector_type(4))) float;  // MFMA C/D frag

// ---- memory plan (bytes) --------------------------------------------------
// x   fp32 residual master        128 MiB
// xb  bf16 copy (GEMM A operand)   64 MiB
// wb  bf16 weights                 25 MiB
// scr bf16 scratch, UNCHUNKED: qkv(1536)+ctx(512) cols in attn phase,
//     hidden(2048) cols in FFN phase -> NTOK*2048*2 = 268.4 MB
// total ~486 MB. Allocated at dlopen (outside graph capture); d_ws used
// instead iff it is big enough (it wasn't in R3-R5: NC=256 chunk evidence).
#define X_BYTES   ((size_t)NTOK * D_ * 4)
#define XB_BYTES  ((size_t)NTOK * D_ * 2)
#define WQ_ELEMS  ((size_t)L_ * 3*D_*D_)
#define WO_ELEMS  ((size_t)L_ * D_*D_)
#define W1_ELEMS  ((size_t)L_ * 4*D_*D_)
#define W2_ELEMS  ((size_t)L_ * 4*D_*D_)
#define WB_BYTES  ((WQ_ELEMS + WO_ELEMS + W1_ELEMS + W2_ELEMS) * 2)
#define SCR_BYTES ((size_t)NTOK * 2048 * 2)
#define TOTAL_BYTES (X_BYTES + XB_BYTES + WB_BYTES + SCR_BYTES)

static char* g_fallback = nullptr;
__attribute__((constructor)) static void alloc_fallback() {
    (void)hipMalloc((void**)&g_fallback, TOTAL_BYTES);
}

// ---- async global->LDS (16B per lane; LDS dest = wave base + lane*16) -----
typedef __attribute__((address_space(3))) uint8_t* as3p;
typedef const __attribute__((address_space(1))) uint8_t* as1p;
__device__ __forceinline__ void gload_lds16(const void* g, void* l) {
    __builtin_amdgcn_global_load_lds((as1p)(const uint8_t*)g,
                                     (as3p)(uint32_t)(uintptr_t)l, 16, 0, 0);
}

__device__ __forceinline__ float bf2f(short s) {
    return __uint_as_float(((uint32_t)(uint16_t)s) << 16);
}

// ---------------------------------------------------------------------------
// weight convert fp32 -> bf16 (4 elems/thread)
// ---------------------------------------------------------------------------
__global__ __launch_bounds__(256) void cvt_kernel(
    const float* __restrict__ w, bf16* __restrict__ o, int n4)
{
    int i = blockIdx.x * 256 + threadIdx.x;
    if (i >= n4) return;
    float4 f = ((const float4*)w)[i];
    bf16* d = o + (size_t)i * 4;
    d[0] = __float2bfloat16(f.x);
    d[1] = __float2bfloat16(f.y);
    d[2] = __float2bfloat16(f.z);
    d[3] = __float2bfloat16(f.w);
}

// ---------------------------------------------------------------------------
// build_x: x[n*32+w,:] = feats[b, max(t+w-31,0),:] + pos[w,:]; also bf16 copy
// ---------------------------------------------------------------------------
__global__ __launch_bounds__(256) void build_x_kernel(
    const float* __restrict__ feats,
    const float* __restrict__ pos,
    float* __restrict__ x,
    bf16* __restrict__ xb)
{
    int gid   = blockIdx.x * 256 + threadIdx.x;   // over NTOK * (D/4)
    int token = gid >> 7;
    int c4    = (gid & 127) * 4;
    int w     = token & (W_-1);
    int n     = token >> 5;
    int t     = n & (T_-1);
    int b     = n >> 8;
    int frame = t + w - (W_-1); if (frame < 0) frame = 0;
    const float4 f = *(const float4*)(feats + ((size_t)(b*T_ + frame)*D_ + c4));
    const float4 p = *(const float4*)(pos   + ((size_t)w*D_ + c4));
    float4 r; r.x = f.x+p.x; r.y = f.y+p.y; r.z = f.z+p.z; r.w = f.w+p.w;
    *(float4*)(x + (size_t)token*D_ + c4) = r;
    bf16* d = xb + (size_t)token*D_ + c4;
    d[0] = __float2bfloat16(r.x);
    d[1] = __float2bfloat16(r.y);
    d[2] = __float2bfloat16(r.z);
    d[3] = __float2bfloat16(r.w);
}

// ---------------------------------------------------------------------------
// bf16 MFMA GEMM (m97 structure): C = A(MxK) @ Bt(NxK)^T + bias [+resid][relu]
// 128x128 tile, BK=32, 256 thr = 4 waves, each wave 64x64 (4x4 16x16x32 MFMA).
// OUTBF: write bf16 Cb; else fp32 C32 (resid may alias C32 - same thread rw).
// M%128==0, N%128==0, K%32==0.
// ---------------------------------------------------------------------------
template<bool RELU, bool RESID, bool OUTBF>
__global__ __launch_bounds__(256) void gemm_mfma(
    const bf16* __restrict__ A,
    const bf16* __restrict__ Bt,
    const float* __restrict__ bias,
    const float* resid,
    float* C32,
    bf16* Cb,
    int M, int N, int K)
{
    __shared__ bf16 As[128*32];   // [row][k] row-major, 64B rows
    __shared__ bf16 Bs[128*32];

    const int tid  = threadIdx.x;
    const int lane = tid & 63;
    const int wv   = tid >> 6;
    const int m0   = blockIdx.y * 128;
    const int n0   = blockIdx.x * 128;
    const int wm   = (wv >> 1) * 64;   // wave row offset in tile
    const int wn   = (wv & 1) * 64;    // wave col offset in tile

    f32x4 acc[4][4] = {};

    // staging: wave wv stages 16 rows per half; lane -> row lane>>2, 16B chunk lane&3
    const int   srow  = wv*16 + (lane >> 2);
    const int   skoff = (lane & 3) * 8;          // elements
    const bf16* ga0 = A  + (size_t)(m0 + srow)      * K + skoff;
    const bf16* ga1 = A  + (size_t)(m0 + 64 + srow) * K + skoff;
    const bf16* gb0 = Bt + (size_t)(n0 + srow)      * K + skoff;
    const bf16* gb1 = Bt + (size_t)(n0 + 64 + srow) * K + skoff;
    char* lAs = (char*)As;
    char* lBs = (char*)Bs;
    const int l0 = wv*1024 + lane*16;            // == srow*64 + (lane&3)*16

    const int fr = lane & 15;                    // fragment row (m or n)
    const int fq = (lane >> 4) * 16;             // 16B k-chunk

    for (int k0 = 0; k0 < K; k0 += 32) {
        gload_lds16(ga0 + k0, lAs + l0);
        gload_lds16(ga1 + k0, lAs + l0 + 4096);
        gload_lds16(gb0 + k0, lBs + l0);
        gload_lds16(gb1 + k0, lBs + l0 + 4096);
        __syncthreads();   // drains vmcnt (DMA) before reads

        bf16x8 av[4], bv[4];
#pragma unroll
        for (int i = 0; i < 4; ++i) {
            av[i] = *(const bf16x8*)(lAs + (wm + i*16 + fr)*64 + fq);
            bv[i] = *(const bf16x8*)(lBs + (wn + i*16 + fr)*64 + fq);
        }
#pragma unroll
        for (int i = 0; i < 4; ++i)
#pragma unroll
            for (int j = 0; j < 4; ++j)
                acc[i][j] = __builtin_amdgcn_mfma_f32_16x16x32_bf16(
                    av[i], bv[j], acc[i][j], 0, 0, 0);
        __syncthreads();   // all waves done reading before next DMA
    }

    // epilogue: C/D layout col=lane&15, row=(lane>>4)*4+reg  [m89/m91 verified]
    const int er = (lane >> 4) * 4;
    const int ec = lane & 15;
#pragma unroll
    for (int i = 0; i < 4; ++i) {
#pragma unroll
        for (int j = 0; j < 4; ++j) {
            const int ncol = n0 + wn + j*16 + ec;
            const float bv_ = bias[ncol];
#pragma unroll
            for (int r = 0; r < 4; ++r) {
                const int mrow = m0 + wm + i*16 + er + r;
                float v = acc[i][j][r] + bv_;
                if (RESID) v += resid[(size_t)mrow * N + ncol];
                if (RELU)  v = fmaxf(v, 0.f);
                if (OUTBF) Cb[(size_t)mrow * N + ncol] = __float2bfloat16(v);
                else       C32[(size_t)mrow * N + ncol] = v;
            }
        }
    }
}

// ---------------------------------------------------------------------------
// Attention: block per (window, head); bf16 qkv in, bf16 ctx out; fp32 inside.
// LDS rows padded to DHP=65 floats (bank-conflict fix, R5: 2.8e7 -> benign).
// ---------------------------------------------------------------------------
__global__ __launch_bounds__(256) void attn_kernel(
    const bf16* __restrict__ qkv,
    bf16* __restrict__ ctx)
{
    const int n = blockIdx.x;
    const int h = blockIdx.y;
    __shared__ float q[W_][DHP];
    __shared__ float k[W_][DHP];
    __shared__ float v[W_][DHP];
    __shared__ float s[W_][W_ + 1];

    const int tid = threadIdx.x;
    {   // load q,k,v: row tid>>3, 8 cols via 16B bf16 loads
        int r  = tid >> 3;
        int c0 = (tid & 7) * 8;
        const bf16* base = qkv + (size_t)(n*W_ + r) * (3*D_) + h*DH_ + c0;
        bf16x8 tq = *(const bf16x8*)(base);
        bf16x8 tk = *(const bf16x8*)(base + D_);
        bf16x8 tv = *(const bf16x8*)(base + 2*D_);
#pragma unroll
        for (int j = 0; j < 8; ++j) {
            q[r][c0 + j] = bf2f(tq[j]);
            k[r][c0 + j] = bf2f(tk[j]);
            v[r][c0 + j] = bf2f(tv[j]);
        }
    }
    __syncthreads();

    const int i = tid >> 3;
    {   // scores
        int j0 = (tid & 7) * 4;
#pragma unroll
        for (int jj = 0; jj < 4; ++jj) {
            int j = j0 + jj;
            float d = 0.f;
#pragma unroll
            for (int kk = 0; kk < DH_; ++kk) d += q[i][kk] * k[j][kk];
            s[i][j] = (j <= i) ? d * 0.125f : -1e30f;
        }
    }
    __syncthreads();

    if (tid < W_) {   // softmax row
        float mx = -1e30f;
#pragma unroll
        for (int j = 0; j < W_; ++j) mx = fmaxf(mx, s[tid][j]);
        float sum = 0.f;
#pragma unroll
        for (int j = 0; j < W_; ++j) { float e = __expf(s[tid][j] - mx); s[tid][j] = e; sum += e; }
        float inv = 1.f / sum;
#pragma unroll
        for (int j = 0; j < W_; ++j) s[tid][j] *= inv;
    }
    __syncthreads();

    {   // ctx
        int d0 = (tid & 7) * 8;
        float o[8] = {0,0,0,0,0,0,0,0};
#pragma unroll
        for (int j = 0; j < W_; ++j) {
            float a = s[i][j];
#pragma unroll
            for (int dd = 0; dd < 8; ++dd) o[dd] += a * v[j][d0 + dd];
        }
        bf16* dst = ctx + (size_t)(n*W_ + i) * D_ + h*DH_ + d0;
#pragma unroll
        for (int dd = 0; dd < 8; ++dd) dst[dd] = __float2bfloat16(o[dd]);
    }
}

// ---------------------------------------------------------------------------
// LayerNorm in place on fp32 x; also writes bf16 copy. One wave per token.
// ---------------------------------------------------------------------------
__global__ __launch_bounds__(256) void ln_kernel(
    float* x, bf16* __restrict__ xb,
    const float* __restrict__ g,
    const float* __restrict__ b)
{
    const int wave  = threadIdx.x >> 6;
    const int lane  = threadIdx.x & 63;
    const int token = blockIdx.x * 4 + wave;
    float* row  = x  + (size_t)token * D_;
    bf16*  rowb = xb + (size_t)token * D_;
    float vals[8];
    float sum = 0.f, sq = 0.f;
#pragma unroll
    for (int j = 0; j < 8; ++j) {
        float t = row[lane + j*64];
        vals[j] = t; sum += t; sq += t*t;
    }
#pragma unroll
    for (int off = 32; off > 0; off >>= 1) {
        sum += __shfl_down(sum, off);
        sq  += __shfl_down(sq,  off);
    }
    sum = __shfl(sum, 0);
    sq  = __shfl(sq, 0);
    const float mu = sum * (1.f / D_);
    float var = sq * (1.f / D_) - mu * mu;
    if (var < 0.f) var = 0.f;
    const float rs = rsqrtf(var + 1e-5f);
#pragma unroll
    for (int j = 0; j < 8; ++j) {
        int d = lane + j*64;
        float o = (vals[j] - mu) * rs * g[d] + b[d];
        row[d]  = o;
        rowb[d] = __float2bfloat16(o);
    }
}

// ---------------------------------------------------------------------------
// Head: token = x[n*32+31,:] fp32; logits (NWIN,6) then values (NWIN)
// ---------------------------------------------------------------------------
__global__ __launch_bounds__(64) void head_kernel(
    const float* __restrict__ x,
    const float* __restrict__ Wp, const float* __restrict__ bp,
    const float* __restrict__ Wv, const float* __restrict__ bv,
    float* __restrict__ out)
{
    const int n    = blockIdx.x;
    const int lane = threadIdx.x;
    const float* row = x + (size_t)(n*W_ + (W_-1)) * D_;
    float t[8];
#pragma unroll
    for (int j = 0; j < 8; ++j) t[j] = row[lane + j*64];

    for (int a = 0; a < A_ + 1; ++a) {
        const float* w = (a < A_) ? (Wp + (size_t)a * D_) : Wv;
        float d = 0.f;
#pragma unroll
        for (int j = 0; j < 8; ++j) d += t[j] * w[lane + j*64];
#pragma unroll
        for (int off = 32; off > 0; off >>= 1) d += __shfl_down(d, off);
        if (lane == 0) {
            if (a < A_) out[(size_t)n*A_ + a] = d + bp[a];
            else        out[(size_t)NWIN*A_ + n] = d + bv[0];
        }
    }
}

// ---------------------------------------------------------------------------
extern "C" void kernel_launch(void* const* d_in, const int* in_sizes, int n_in,
                              void* d_out, int out_size, void* d_ws, size_t ws_size,
                              hipStream_t stream) {
    const float* feats = (const float*)d_in[0];
    const float* pos   = (const float*)d_in[1];
    const float* Wqkv  = (const float*)d_in[2];
    const float* bqkv  = (const float*)d_in[3];
    const float* Wo    = (const float*)d_in[4];
    const float* bo    = (const float*)d_in[5];
    const float* ln1g  = (const float*)d_in[6];
    const float* ln1b  = (const float*)d_in[7];
    const float* W1    = (const float*)d_in[8];
    const float* b1    = (const float*)d_in[9];
    const float* W2    = (const float*)d_in[10];
    const float* b2    = (const float*)d_in[11];
    const float* ln2g  = (const float*)d_in[12];
    const float* ln2b  = (const float*)d_in[13];
    const float* Wp    = (const float*)d_in[14];
    const float* bp    = (const float*)d_in[15];
    const float* Wv    = (const float*)d_in[16];
    const float* bv    = (const float*)d_in[17];
    float* out = (float*)d_out;

    // prefer d_ws when it fits the full unchunked plan; else our own buffer
    char* basep = (ws_size >= TOTAL_BYTES) ? (char*)d_ws : g_fallback;

    float* x    = (float*)basep;
    bf16*  xb   = (bf16*)(basep + X_BYTES);
    bf16*  wq_b = (bf16*)(basep + X_BYTES + XB_BYTES);
    bf16*  wo_b = wq_b + WQ_ELEMS;
    bf16*  w1_b = wo_b + WO_ELEMS;
    bf16*  w2_b = w1_b + W1_ELEMS;
    bf16*  scr  = w2_b + W2_ELEMS;
    bf16*  qkv_s = scr;                            // (NTOK, 1536)
    bf16*  ctx_s = scr + (size_t)NTOK * (3*D_);    // (NTOK, 512)
    bf16*  h_s   = scr;                            // (NTOK, 2048) FFN phase

    // convert weights to bf16 (weights restored pristine each call)
    cvt_kernel<<<(WQ_ELEMS/4 + 255)/256, 256, 0, stream>>>(Wqkv, wq_b, WQ_ELEMS/4);
    cvt_kernel<<<(WO_ELEMS/4 + 255)/256, 256, 0, stream>>>(Wo,   wo_b, WO_ELEMS/4);
    cvt_kernel<<<(W1_ELEMS/4 + 255)/256, 256, 0, stream>>>(W1,   w1_b, W1_ELEMS/4);
    cvt_kernel<<<(W2_ELEMS/4 + 255)/256, 256, 0, stream>>>(W2,   w2_b, W2_ELEMS/4);

    build_x_kernel<<<NTOK * (D_/4) / 256, 256, 0, stream>>>(feats, pos, x, xb);

    for (int i = 0; i < L_; ++i) {
        const bf16*  wq_i = wq_b + (size_t)i * 3*D_*D_;
        const float* bq_i = bqkv + (size_t)i * 3*D_;
        const bf16*  wo_i = wo_b + (size_t)i * D_*D_;
        const float* bo_i = bo   + (size_t)i * D_;
        const bf16*  w1_i = w1_b + (size_t)i * 4*D_*D_;
        const float* b1_i = b1   + (size_t)i * 4*D_;
        const bf16*  w2_i = w2_b + (size_t)i * 4*D_*D_;
        const float* b2_i = b2   + (size_t)i * D_;

        // ---- attention phase (full batch, no chunking) ----
        gemm_mfma<false,false,true><<<dim3(3*D_/128, NTOK/128), 256, 0, stream>>>(
            xb, wq_i, bq_i, nullptr, nullptr, qkv_s, NTOK, 3*D_, D_);
        attn_kernel<<<dim3(NWIN, H_), 256, 0, stream>>>(qkv_s, ctx_s);
        gemm_mfma<false,true,false><<<dim3(D_/128, NTOK/128), 256, 0, stream>>>(
            ctx_s, wo_i, bo_i, x, x, nullptr, NTOK, D_, D_);
        ln_kernel<<<NTOK/4, 256, 0, stream>>>(x, xb, ln1g + (size_t)i*D_, ln1b + (size_t)i*D_);

        // ---- FFN phase (full batch) ----
        gemm_mfma<true,false,true><<<dim3(4*D_/128, NTOK/128), 256, 0, stream>>>(
            xb, w1_i, b1_i, nullptr, nullptr, h_s, NTOK, 4*D_, D_);
        gemm_mfma<false,true,false><<<dim3(D_/128, NTOK/128), 256, 0, stream>>>(
            h_s, w2_i, b2_i, x, x, nullptr, NTOK, D_, 4*D_);
        ln_kernel<<<NTOK/4, 256, 0, stream>>>(x, xb, ln2g + (size_t)i*D_, ln2b + (size_t)i*D_);
    }

    head_kernel<<<NWIN, 64, 0, stream>>>(x, Wp, bp, Wv, bv, out);
}

// Round 7
// 4772.876 us; speedup vs baseline: 5.2115x; 1.0246x over previous
//
#include <hip/hip_runtime.h>
#include <hip/hip_bf16.h>
#include <cstdint>
#include <cstddef>

// Problem constants (fixed by reference)
#define B_    8
#define T_    256
#define D_    512
#define W_    32
#define L_    4
#define A_    6
#define H_    8
#define DH_   64
#define DHP   65                 // padded LDS row: bank (r*65+c)%32 varies with r
#define NWIN  (B_*T_)            // 2048 windows
#define NTOK  (NWIN*W_)          // 65536 token rows

typedef __hip_bfloat16 bf16;
using bf16x8 = __attribute__((ext_vector_type(8))) short;  // MFMA A/B frag (4 VGPR)
using f32x4  = __attribute__((ext_vector_type(4))) float;  // MFMA C/D frag

// ---- memory plan (bytes) --------------------------------------------------
#define X_BYTES   ((size_t)NTOK * D_ * 4)
#define XB_BYTES  ((size_t)NTOK * D_ * 2)
#define WQ_ELEMS  ((size_t)L_ * 3*D_*D_)
#define WO_ELEMS  ((size_t)L_ * D_*D_)
#define W1_ELEMS  ((size_t)L_ * 4*D_*D_)
#define W2_ELEMS  ((size_t)L_ * 4*D_*D_)
#define WB_BYTES  ((WQ_ELEMS + WO_ELEMS + W1_ELEMS + W2_ELEMS) * 2)
#define SCR_BYTES ((size_t)NTOK * 2048 * 2)
#define TOTAL_BYTES (X_BYTES + XB_BYTES + WB_BYTES + SCR_BYTES)

static char* g_fallback = nullptr;
__attribute__((constructor)) static void alloc_fallback() {
    (void)hipMalloc((void**)&g_fallback, TOTAL_BYTES);
}

// ---- async global->LDS (16B per lane; LDS dest = wave base + lane*16) -----
typedef __attribute__((address_space(3))) uint8_t* as3p;
typedef const __attribute__((address_space(1))) uint8_t* as1p;
__device__ __forceinline__ void gload_lds16(const void* g, void* l) {
    __builtin_amdgcn_global_load_lds((as1p)(const uint8_t*)g,
                                     (as3p)(uint32_t)(uintptr_t)l, 16, 0, 0);
}

__device__ __forceinline__ float bf2f(short s) {
    return __uint_as_float(((uint32_t)(uint16_t)s) << 16);
}

// ---------------------------------------------------------------------------
// weight convert fp32 -> bf16 (4 elems/thread)
// ---------------------------------------------------------------------------
__global__ __launch_bounds__(256) void cvt_kernel(
    const float* __restrict__ w, bf16* __restrict__ o, int n4)
{
    int i = blockIdx.x * 256 + threadIdx.x;
    if (i >= n4) return;
    float4 f = ((const float4*)w)[i];
    bf16* d = o + (size_t)i * 4;
    d[0] = __float2bfloat16(f.x);
    d[1] = __float2bfloat16(f.y);
    d[2] = __float2bfloat16(f.z);
    d[3] = __float2bfloat16(f.w);
}

// ---------------------------------------------------------------------------
// build_x: x[n*32+w,:] = feats[b, max(t+w-31,0),:] + pos[w,:]; also bf16 copy
// ---------------------------------------------------------------------------
__global__ __launch_bounds__(256) void build_x_kernel(
    const float* __restrict__ feats,
    const float* __restrict__ pos,
    float* __restrict__ x,
    bf16* __restrict__ xb)
{
    int gid   = blockIdx.x * 256 + threadIdx.x;   // over NTOK * (D/4)
    int token = gid >> 7;
    int c4    = (gid & 127) * 4;
    int w     = token & (W_-1);
    int n     = token >> 5;
    int t     = n & (T_-1);
    int b     = n >> 8;
    int frame = t + w - (W_-1); if (frame < 0) frame = 0;
    const float4 f = *(const float4*)(feats + ((size_t)(b*T_ + frame)*D_ + c4));
    const float4 p = *(const float4*)(pos   + ((size_t)w*D_ + c4));
    float4 r; r.x = f.x+p.x; r.y = f.y+p.y; r.z = f.z+p.z; r.w = f.w+p.w;
    *(float4*)(x + (size_t)token*D_ + c4) = r;
    bf16* d = xb + (size_t)token*D_ + c4;
    d[0] = __float2bfloat16(r.x);
    d[1] = __float2bfloat16(r.y);
    d[2] = __float2bfloat16(r.z);
    d[3] = __float2bfloat16(r.w);
}

// ---------------------------------------------------------------------------
// bf16 MFMA GEMM: C = A(MxK) @ Bt(NxK)^T + bias [+resid][relu]
// 128x128 tile, BK=32, 256 thr = 4 waves, each wave 64x64 (4x4 16x16x32 MFMA).
// 1-D grid with XCD-aware remap: the gridN blocks that share one 128-row
// A-stripe get bids differing by 8 -> same XCD (bid&7 heuristic) -> A-stripe
// fetched once into that XCD's L2 and reused gridN times (R6: W2 FETCH was
// 648 MB vs 402 ideal because same-A blocks landed on different XCD L2s).
// Requires gridM (=M/128) % 8 == 0 (M=65536 -> 512 here, always).
// ---------------------------------------------------------------------------
template<bool RELU, bool RESID, bool OUTBF>
__global__ __launch_bounds__(256) void gemm_mfma(
    const bf16* __restrict__ A,
    const bf16* __restrict__ Bt,
    const float* __restrict__ bias,
    const float* resid,
    float* C32,
    bf16* Cb,
    int M, int N, int K)
{
    __shared__ bf16 As[128*32];   // [row][k] row-major, 64B rows
    __shared__ bf16 Bs[128*32];

    const int tid  = threadIdx.x;
    const int lane = tid & 63;
    const int wv   = tid >> 6;

    // XCD-aware block remap
    const int gridN = N >> 7;
    const int bid   = blockIdx.x;
    const int xcd   = bid & 7;
    const int q     = bid >> 3;
    const int n_idx = q % gridN;
    const int m_idx = (q / gridN) * 8 + xcd;
    const int m0    = m_idx << 7;
    const int n0    = n_idx << 7;

    const int wm   = (wv >> 1) * 64;   // wave row offset in tile
    const int wn   = (wv & 1) * 64;    // wave col offset in tile

    f32x4 acc[4][4] = {};

    // staging: wave wv stages 16 rows per half; lane -> row lane>>2, 16B chunk lane&3
    const int   srow  = wv*16 + (lane >> 2);
    const int   skoff = (lane & 3) * 8;          // elements
    const bf16* ga0 = A  + (size_t)(m0 + srow)      * K + skoff;
    const bf16* ga1 = A  + (size_t)(m0 + 64 + srow) * K + skoff;
    const bf16* gb0 = Bt + (size_t)(n0 + srow)      * K + skoff;
    const bf16* gb1 = Bt + (size_t)(n0 + 64 + srow) * K + skoff;
    char* lAs = (char*)As;
    char* lBs = (char*)Bs;
    const int l0 = wv*1024 + lane*16;            // == srow*64 + (lane&3)*16

    const int fr = lane & 15;                    // fragment row (m or n)
    const int fq = (lane >> 4) * 16;             // 16B k-chunk

    for (int k0 = 0; k0 < K; k0 += 32) {
        gload_lds16(ga0 + k0, lAs + l0);
        gload_lds16(ga1 + k0, lAs + l0 + 4096);
        gload_lds16(gb0 + k0, lBs + l0);
        gload_lds16(gb1 + k0, lBs + l0 + 4096);
        __syncthreads();   // drains vmcnt (DMA) before reads

        bf16x8 av[4], bv[4];
#pragma unroll
        for (int i = 0; i < 4; ++i) {
            av[i] = *(const bf16x8*)(lAs + (wm + i*16 + fr)*64 + fq);
            bv[i] = *(const bf16x8*)(lBs + (wn + i*16 + fr)*64 + fq);
        }
#pragma unroll
        for (int i = 0; i < 4; ++i)
#pragma unroll
            for (int j = 0; j < 4; ++j)
                acc[i][j] = __builtin_amdgcn_mfma_f32_16x16x32_bf16(
                    av[i], bv[j], acc[i][j], 0, 0, 0);
        __syncthreads();   // all waves done reading before next DMA
    }

    // epilogue: C/D layout col=lane&15, row=(lane>>4)*4+reg  [m89/m91 verified]
    const int er = (lane >> 4) * 4;
    const int ec = lane & 15;
#pragma unroll
    for (int i = 0; i < 4; ++i) {
#pragma unroll
        for (int j = 0; j < 4; ++j) {
            const int ncol = n0 + wn + j*16 + ec;
            const float bv_ = bias[ncol];
#pragma unroll
            for (int r = 0; r < 4; ++r) {
                const int mrow = m0 + wm + i*16 + er + r;
                float v = acc[i][j][r] + bv_;
                if (RESID) v += resid[(size_t)mrow * N + ncol];
                if (RELU)  v = fmaxf(v, 0.f);
                if (OUTBF) Cb[(size_t)mrow * N + ncol] = __float2bfloat16(v);
                else       C32[(size_t)mrow * N + ncol] = v;
            }
        }
    }
}

// ---------------------------------------------------------------------------
// Attention: block per (window, head); bf16 qkv in, bf16 ctx out; fp32 inside.
// LDS rows padded to DHP=65 floats (bank-conflict fix, R5: 2.8e7 -> benign).
// ---------------------------------------------------------------------------
__global__ __launch_bounds__(256) void attn_kernel(
    const bf16* __restrict__ qkv,
    bf16* __restrict__ ctx)
{
    const int n = blockIdx.x;
    const int h = blockIdx.y;
    __shared__ float q[W_][DHP];
    __shared__ float k[W_][DHP];
    __shared__ float v[W_][DHP];
    __shared__ float s[W_][W_ + 1];

    const int tid = threadIdx.x;
    {   // load q,k,v: row tid>>3, 8 cols via 16B bf16 loads
        int r  = tid >> 3;
        int c0 = (tid & 7) * 8;
        const bf16* base = qkv + (size_t)(n*W_ + r) * (3*D_) + h*DH_ + c0;
        bf16x8 tq = *(const bf16x8*)(base);
        bf16x8 tk = *(const bf16x8*)(base + D_);
        bf16x8 tv = *(const bf16x8*)(base + 2*D_);
#pragma unroll
        for (int j = 0; j < 8; ++j) {
            q[r][c0 + j] = bf2f(tq[j]);
            k[r][c0 + j] = bf2f(tk[j]);
            v[r][c0 + j] = bf2f(tv[j]);
        }
    }
    __syncthreads();

    const int i = tid >> 3;
    {   // scores
        int j0 = (tid & 7) * 4;
#pragma unroll
        for (int jj = 0; jj < 4; ++jj) {
            int j = j0 + jj;
            float d = 0.f;
#pragma unroll
            for (int kk = 0; kk < DH_; ++kk) d += q[i][kk] * k[j][kk];
            s[i][j] = (j <= i) ? d * 0.125f : -1e30f;
        }
    }
    __syncthreads();

    if (tid < W_) {   // softmax row
        float mx = -1e30f;
#pragma unroll
        for (int j = 0; j < W_; ++j) mx = fmaxf(mx, s[tid][j]);
        float sum = 0.f;
#pragma unroll
        for (int j = 0; j < W_; ++j) { float e = __expf(s[tid][j] - mx); s[tid][j] = e; sum += e; }
        float inv = 1.f / sum;
#pragma unroll
        for (int j = 0; j < W_; ++j) s[tid][j] *= inv;
    }
    __syncthreads();

    {   // ctx
        int d0 = (tid & 7) * 8;
        float o[8] = {0,0,0,0,0,0,0,0};
#pragma unroll
        for (int j = 0; j < W_; ++j) {
            float a = s[i][j];
#pragma unroll
            for (int dd = 0; dd < 8; ++dd) o[dd] += a * v[j][d0 + dd];
        }
        bf16* dst = ctx + (size_t)(n*W_ + i) * D_ + h*DH_ + d0;
#pragma unroll
        for (int dd = 0; dd < 8; ++dd) dst[dd] = __float2bfloat16(o[dd]);
    }
}

// ---------------------------------------------------------------------------
// LayerNorm in place on fp32 x; also writes bf16 copy. One wave per token.
// ---------------------------------------------------------------------------
__global__ __launch_bounds__(256) void ln_kernel(
    float* x, bf16* __restrict__ xb,
    const float* __restrict__ g,
    const float* __restrict__ b)
{
    const int wave  = threadIdx.x >> 6;
    const int lane  = threadIdx.x & 63;
    const int token = blockIdx.x * 4 + wave;
    float* row  = x  + (size_t)token * D_;
    bf16*  rowb = xb + (size_t)token * D_;
    float vals[8];
    float sum = 0.f, sq = 0.f;
#pragma unroll
    for (int j = 0; j < 8; ++j) {
        float t = row[lane + j*64];
        vals[j] = t; sum += t; sq += t*t;
    }
#pragma unroll
    for (int off = 32; off > 0; off >>= 1) {
        sum += __shfl_down(sum, off);
        sq  += __shfl_down(sq,  off);
    }
    sum = __shfl(sum, 0);
    sq  = __shfl(sq, 0);
    const float mu = sum * (1.f / D_);
    float var = sq * (1.f / D_) - mu * mu;
    if (var < 0.f) var = 0.f;
    const float rs = rsqrtf(var + 1e-5f);
#pragma unroll
    for (int j = 0; j < 8; ++j) {
        int d = lane + j*64;
        float o = (vals[j] - mu) * rs * g[d] + b[d];
        row[d]  = o;
        rowb[d] = __float2bfloat16(o);
    }
}

// ---------------------------------------------------------------------------
// Head: token = x[n*32+31,:] fp32; logits (NWIN,6) then values (NWIN)
// ---------------------------------------------------------------------------
__global__ __launch_bounds__(64) void head_kernel(
    const float* __restrict__ x,
    const float* __restrict__ Wp, const float* __restrict__ bp,
    const float* __restrict__ Wv, const float* __restrict__ bv,
    float* __restrict__ out)
{
    const int n    = blockIdx.x;
    const int lane = threadIdx.x;
    const float* row = x + (size_t)(n*W_ + (W_-1)) * D_;
    float t[8];
#pragma unroll
    for (int j = 0; j < 8; ++j) t[j] = row[lane + j*64];

    for (int a = 0; a < A_ + 1; ++a) {
        const float* w = (a < A_) ? (Wp + (size_t)a * D_) : Wv;
        float d = 0.f;
#pragma unroll
        for (int j = 0; j < 8; ++j) d += t[j] * w[lane + j*64];
#pragma unroll
        for (int off = 32; off > 0; off >>= 1) d += __shfl_down(d, off);
        if (lane == 0) {
            if (a < A_) out[(size_t)n*A_ + a] = d + bp[a];
            else        out[(size_t)NWIN*A_ + n] = d + bv[0];
        }
    }
}

// ---------------------------------------------------------------------------
extern "C" void kernel_launch(void* const* d_in, const int* in_sizes, int n_in,
                              void* d_out, int out_size, void* d_ws, size_t ws_size,
                              hipStream_t stream) {
    const float* feats = (const float*)d_in[0];
    const float* pos   = (const float*)d_in[1];
    const float* Wqkv  = (const float*)d_in[2];
    const float* bqkv  = (const float*)d_in[3];
    const float* Wo    = (const float*)d_in[4];
    const float* bo    = (const float*)d_in[5];
    const float* ln1g  = (const float*)d_in[6];
    const float* ln1b  = (const float*)d_in[7];
    const float* W1    = (const float*)d_in[8];
    const float* b1    = (const float*)d_in[9];
    const float* W2    = (const float*)d_in[10];
    const float* b2    = (const float*)d_in[11];
    const float* ln2g  = (const float*)d_in[12];
    const float* ln2b  = (const float*)d_in[13];
    const float* Wp    = (const float*)d_in[14];
    const float* bp    = (const float*)d_in[15];
    const float* Wv    = (const float*)d_in[16];
    const float* bv    = (const float*)d_in[17];
    float* out = (float*)d_out;

    // prefer d_ws when it fits the full unchunked plan; else our own buffer
    char* basep = (ws_size >= TOTAL_BYTES) ? (char*)d_ws : g_fallback;

    float* x    = (float*)basep;
    bf16*  xb   = (bf16*)(basep + X_BYTES);
    bf16*  wq_b = (bf16*)(basep + X_BYTES + XB_BYTES);
    bf16*  wo_b = wq_b + WQ_ELEMS;
    bf16*  w1_b = wo_b + WO_ELEMS;
    bf16*  w2_b = w1_b + W1_ELEMS;
    bf16*  scr  = w2_b + W2_ELEMS;
    bf16*  qkv_s = scr;                            // (NTOK, 1536)
    bf16*  ctx_s = scr + (size_t)NTOK * (3*D_);    // (NTOK, 512)
    bf16*  h_s   = scr;                            // (NTOK, 2048) FFN phase

    // convert weights to bf16 (weights restored pristine each call)
    cvt_kernel<<<(WQ_ELEMS/4 + 255)/256, 256, 0, stream>>>(Wqkv, wq_b, WQ_ELEMS/4);
    cvt_kernel<<<(WO_ELEMS/4 + 255)/256, 256, 0, stream>>>(Wo,   wo_b, WO_ELEMS/4);
    cvt_kernel<<<(W1_ELEMS/4 + 255)/256, 256, 0, stream>>>(W1,   w1_b, W1_ELEMS/4);
    cvt_kernel<<<(W2_ELEMS/4 + 255)/256, 256, 0, stream>>>(W2,   w2_b, W2_ELEMS/4);

    build_x_kernel<<<NTOK * (D_/4) / 256, 256, 0, stream>>>(feats, pos, x, xb);

    const int GM = NTOK / 128;   // 512 m-blocks, divisible by 8

    for (int i = 0; i < L_; ++i) {
        const bf16*  wq_i = wq_b + (size_t)i * 3*D_*D_;
        const float* bq_i = bqkv + (size_t)i * 3*D_;
        const bf16*  wo_i = wo_b + (size_t)i * D_*D_;
        const float* bo_i = bo   + (size_t)i * D_;
        const bf16*  w1_i = w1_b + (size_t)i * 4*D_*D_;
        const float* b1_i = b1   + (size_t)i * 4*D_;
        const bf16*  w2_i = w2_b + (size_t)i * 4*D_*D_;
        const float* b2_i = b2   + (size_t)i * D_;

        // ---- attention phase (full batch) ----
        gemm_mfma<false,false,true><<<GM * (3*D_/128), 256, 0, stream>>>(
            xb, wq_i, bq_i, nullptr, nullptr, qkv_s, NTOK, 3*D_, D_);
        attn_kernel<<<dim3(NWIN, H_), 256, 0, stream>>>(qkv_s, ctx_s);
        gemm_mfma<false,true,false><<<GM * (D_/128), 256, 0, stream>>>(
            ctx_s, wo_i, bo_i, x, x, nullptr, NTOK, D_, D_);
        ln_kernel<<<NTOK/4, 256, 0, stream>>>(x, xb, ln1g + (size_t)i*D_, ln1b + (size_t)i*D_);

        // ---- FFN phase (full batch) ----
        gemm_mfma<true,false,true><<<GM * (4*D_/128), 256, 0, stream>>>(
            xb, w1_i, b1_i, nullptr, nullptr, h_s, NTOK, 4*D_, D_);
        gemm_mfma<false,true,false><<<GM * (D_/128), 256, 0, stream>>>(
            h_s, w2_i, b2_i, x, x, nullptr, NTOK, D_, 4*D_);
        ln_kernel<<<NTOK/4, 256, 0, stream>>>(x, xb, ln2g + (size_t)i*D_, ln2b + (size_t)i*D_);
    }

    head_kernel<<<NWIN, 64, 0, stream>>>(x, Wp, bp, Wv, bv, out);
}

// Round 8
// 4248.380 us; speedup vs baseline: 5.8549x; 1.1235x over previous
//
#include <hip/hip_runtime.h>
#include <hip/hip_bf16.h>
#include <cstdint>
#include <cstddef>

// Problem constants (fixed by reference)
#define B_    8
#define T_    256
#define D_    512
#define W_    32
#define L_    4
#define A_    6
#define H_    8
#define DH_   64
#define DHP   65                 // padded LDS row (attn bank-conflict fix, R5)
#define NWIN  (B_*T_)            // 2048 windows
#define NTOK  (NWIN*W_)          // 65536 token rows

typedef __hip_bfloat16 bf16;
using bf16x8 = __attribute__((ext_vector_type(8))) short;  // MFMA A/B frag (4 VGPR)
using f32x4  = __attribute__((ext_vector_type(4))) float;  // MFMA C/D frag

// ---- memory plan (bytes): bf16-only residual stream ----------------------
#define XB_BYTES  ((size_t)NTOK * D_ * 2)     // 64 MiB bf16 residual master
#define WQ_ELEMS  ((size_t)L_ * 3*D_*D_)
#define WO_ELEMS  ((size_t)L_ * D_*D_)
#define W1_ELEMS  ((size_t)L_ * 4*D_*D_)
#define W2_ELEMS  ((size_t)L_ * 4*D_*D_)
#define WB_BYTES  ((WQ_ELEMS + WO_ELEMS + W1_ELEMS + W2_ELEMS) * 2)
#define SCR_BYTES ((size_t)NTOK * 2048 * 2)   // qkv(1536)+ctx(512) / h(2048)
#define TOTAL_BYTES (XB_BYTES + WB_BYTES + SCR_BYTES)

static char* g_fallback = nullptr;
__attribute__((constructor)) static void alloc_fallback() {
    (void)hipMalloc((void**)&g_fallback, TOTAL_BYTES);
}

// ---- async global->LDS (16B per lane; LDS dest = wave base + lane*16) -----
typedef __attribute__((address_space(3))) uint8_t* as3p;
typedef const __attribute__((address_space(1))) uint8_t* as1p;
__device__ __forceinline__ void gload_lds16(const void* g, void* l) {
    __builtin_amdgcn_global_load_lds((as1p)(const uint8_t*)g,
                                     (as3p)(uint32_t)(uintptr_t)l, 16, 0, 0);
}

__device__ __forceinline__ float bf2f(short s) {
    return __uint_as_float(((uint32_t)(uint16_t)s) << 16);
}

// ---------------------------------------------------------------------------
// weight convert fp32 -> bf16 (4 elems/thread)
// ---------------------------------------------------------------------------
__global__ __launch_bounds__(256) void cvt_kernel(
    const float* __restrict__ w, bf16* __restrict__ o, int n4)
{
    int i = blockIdx.x * 256 + threadIdx.x;
    if (i >= n4) return;
    float4 f = ((const float4*)w)[i];
    bf16* d = o + (size_t)i * 4;
    d[0] = __float2bfloat16(f.x);
    d[1] = __float2bfloat16(f.y);
    d[2] = __float2bfloat16(f.z);
    d[3] = __float2bfloat16(f.w);
}

// ---------------------------------------------------------------------------
// build_x: xb[n*32+w,:] = bf16(feats[b, max(t+w-31,0),:] + pos[w,:])
// ---------------------------------------------------------------------------
__global__ __launch_bounds__(256) void build_x_kernel(
    const float* __restrict__ feats,
    const float* __restrict__ pos,
    bf16* __restrict__ xb)
{
    int gid   = blockIdx.x * 256 + threadIdx.x;   // over NTOK * (D/4)
    int token = gid >> 7;
    int c4    = (gid & 127) * 4;
    int w     = token & (W_-1);
    int n     = token >> 5;
    int t     = n & (T_-1);
    int b     = n >> 8;
    int frame = t + w - (W_-1); if (frame < 0) frame = 0;
    const float4 f = *(const float4*)(feats + ((size_t)(b*T_ + frame)*D_ + c4));
    const float4 p = *(const float4*)(pos   + ((size_t)w*D_ + c4));
    bf16* d = xb + (size_t)token*D_ + c4;
    d[0] = __float2bfloat16(f.x + p.x);
    d[1] = __float2bfloat16(f.y + p.y);
    d[2] = __float2bfloat16(f.z + p.z);
    d[3] = __float2bfloat16(f.w + p.w);
}

// ---------------------------------------------------------------------------
// bf16 MFMA GEMM (no resid): Cb = bf16(A(MxK) @ Bt(NxK)^T + bias [relu])
// 128x128 tile, BK=32, 4 waves, wave 64x64 (4x4 of 16x16x32 MFMA).
// 1-D grid + XCD remap (R7: same-A-stripe blocks share one XCD L2).
// ---------------------------------------------------------------------------
template<bool RELU>
__global__ __launch_bounds__(256) void gemm_bf16(
    const bf16* __restrict__ A,
    const bf16* __restrict__ Bt,
    const float* __restrict__ bias,
    bf16* __restrict__ Cb,
    int M, int N, int K)
{
    __shared__ bf16 As[128*32];   // [row][k] row-major, 64B rows
    __shared__ bf16 Bs[128*32];

    const int tid  = threadIdx.x;
    const int lane = tid & 63;
    const int wv   = tid >> 6;

    // XCD-aware block remap (gridM % 8 == 0)
    const int gridN = N >> 7;
    const int bid   = blockIdx.x;
    const int q_    = bid >> 3;
    const int n0    = (q_ % gridN) << 7;
    const int m0    = (((q_ / gridN) * 8) + (bid & 7)) << 7;

    const int wm   = (wv >> 1) * 64;
    const int wn   = (wv & 1) * 64;

    f32x4 acc[4][4] = {};

    const int   srow  = wv*16 + (lane >> 2);
    const int   skoff = (lane & 3) * 8;
    const bf16* ga0 = A  + (size_t)(m0 + srow)      * K + skoff;
    const bf16* ga1 = A  + (size_t)(m0 + 64 + srow) * K + skoff;
    const bf16* gb0 = Bt + (size_t)(n0 + srow)      * K + skoff;
    const bf16* gb1 = Bt + (size_t)(n0 + 64 + srow) * K + skoff;
    char* lAs = (char*)As;
    char* lBs = (char*)Bs;
    const int l0 = wv*1024 + lane*16;

    const int fr = lane & 15;
    const int fq = (lane >> 4) * 16;

    for (int k0 = 0; k0 < K; k0 += 32) {
        gload_lds16(ga0 + k0, lAs + l0);
        gload_lds16(ga1 + k0, lAs + l0 + 4096);
        gload_lds16(gb0 + k0, lBs + l0);
        gload_lds16(gb1 + k0, lBs + l0 + 4096);
        __syncthreads();

        bf16x8 av[4], bv[4];
#pragma unroll
        for (int i = 0; i < 4; ++i) {
            av[i] = *(const bf16x8*)(lAs + (wm + i*16 + fr)*64 + fq);
            bv[i] = *(const bf16x8*)(lBs + (wn + i*16 + fr)*64 + fq);
        }
#pragma unroll
        for (int i = 0; i < 4; ++i)
#pragma unroll
            for (int j = 0; j < 4; ++j)
                acc[i][j] = __builtin_amdgcn_mfma_f32_16x16x32_bf16(
                    av[i], bv[j], acc[i][j], 0, 0, 0);
        __syncthreads();
    }

    // epilogue: C/D layout col=lane&15, row=(lane>>4)*4+reg
    const int er = (lane >> 4) * 4;
    const int ec = lane & 15;
#pragma unroll
    for (int i = 0; i < 4; ++i) {
#pragma unroll
        for (int j = 0; j < 4; ++j) {
            const int ncol = n0 + wn + j*16 + ec;
            const float bv_ = bias[ncol];
#pragma unroll
            for (int r = 0; r < 4; ++r) {
                const int mrow = m0 + wm + i*16 + er + r;
                float v = acc[i][j][r] + bv_;
                if (RELU) v = fmaxf(v, 0.f);
                Cb[(size_t)mrow * N + ncol] = __float2bfloat16(v);
            }
        }
    }
}

// ---------------------------------------------------------------------------
// Fused residual GEMM + LayerNorm:
//   y = xres + A @ Bt^T + bias;  xout = LN(y) * g + b      (N fixed = 512)
// Tile 32 rows x 512 cols per block -> block owns full rows, LN in-block.
// 4 waves: wave w covers all 32 rows x cols [w*128, w*128+128); acc 2x8 f32x4.
// Row stats: in-lane sum over 8 j-blocks -> shfl_xor over the 16 lanes of a
// row-group -> cross-wave via LDS red[4][32][2]. In-place xres==xout is safe:
// each block reads/writes only its own 32 rows.
// ---------------------------------------------------------------------------
__global__ __launch_bounds__(256) void gemm_ln(
    const bf16* __restrict__ A,     // (M x K)
    const bf16* __restrict__ Bt,    // (512 x K)
    const float* __restrict__ bias, // (512)
    const bf16* xres,               // (M x 512), aliases xout
    bf16* xout,
    const float* __restrict__ g,
    const float* __restrict__ b,
    int K)
{
    __shared__ bf16 As[32*32];      // 2 KB, 64B rows
    __shared__ bf16 Bs[512*32];     // 32 KB, 64B rows
    __shared__ float red[4][32][2]; // per-wave row partials

    const int tid  = threadIdx.x;
    const int lane = tid & 63;
    const int wv   = tid >> 6;
    const int m0   = blockIdx.x * 32;

    f32x4 acc[2][8] = {};

    // staging addresses
    const bf16* gaA = A + (size_t)(m0 + (tid >> 2)) * K + (tid & 3) * 8; // tid<128
    const int   brow = wv*16 + (lane >> 2);       // within 64-row group
    const int   bkof = (lane & 3) * 8;
    char* lAs = (char*)As;
    char* lBs = (char*)Bs;
    const int l0 = wv*1024 + lane*16;

    const int fr = lane & 15;
    const int fq = (lane >> 4) * 16;
    const int wc = wv * 128;                      // wave col offset

    for (int k0 = 0; k0 < K; k0 += 32) {
        if (tid < 128) gload_lds16(gaA + k0, lAs + tid*16);
#pragma unroll
        for (int jj = 0; jj < 8; ++jj) {
            const bf16* gb = Bt + (size_t)(jj*64 + brow) * K + k0 + bkof;
            gload_lds16(gb, lBs + jj*4096 + l0);
        }
        __syncthreads();

        bf16x8 av[2], bv[8];
#pragma unroll
        for (int i = 0; i < 2; ++i)
            av[i] = *(const bf16x8*)(lAs + (i*16 + fr)*64 + fq);
#pragma unroll
        for (int j = 0; j < 8; ++j)
            bv[j] = *(const bf16x8*)(lBs + (wc + j*16 + fr)*64 + fq);
#pragma unroll
        for (int i = 0; i < 2; ++i)
#pragma unroll
            for (int j = 0; j < 8; ++j)
                acc[i][j] = __builtin_amdgcn_mfma_f32_16x16x32_bf16(
                    av[i], bv[j], acc[i][j], 0, 0, 0);
        __syncthreads();
    }

    // ---- epilogue: v = acc + bias + resid; LN over the 512-wide row ----
    const int er = (lane >> 4) * 4;   // row base within 16-block
    const int ec = lane & 15;         // col within 16-block

    float bias_j[8];
#pragma unroll
    for (int j = 0; j < 8; ++j) bias_j[j] = bias[wc + j*16 + ec];

#pragma unroll
    for (int i = 0; i < 2; ++i) {
#pragma unroll
        for (int r = 0; r < 4; ++r) {
            const int row = i*16 + er + r;
            const bf16* xr = xres + (size_t)(m0 + row) * D_ + wc + ec;
            float s1 = 0.f, s2 = 0.f;
#pragma unroll
            for (int j = 0; j < 8; ++j) {
                float v = acc[i][j][r] + bias_j[j] + bf2f(*(const short*)(xr + j*16));
                acc[i][j][r] = v;
                s1 += v; s2 += v*v;
            }
            // reduce across the 16 lanes (ec) holding this row in this wave
#pragma unroll
            for (int mask = 1; mask < 16; mask <<= 1) {
                s1 += __shfl_xor(s1, mask, 64);
                s2 += __shfl_xor(s2, mask, 64);
            }
            if (ec == 0) { red[wv][row][0] = s1; red[wv][row][1] = s2; }
        }
    }
    __syncthreads();

#pragma unroll
    for (int i = 0; i < 2; ++i) {
#pragma unroll
        for (int r = 0; r < 4; ++r) {
            const int row = i*16 + er + r;
            float t1 = red[0][row][0] + red[1][row][0] + red[2][row][0] + red[3][row][0];
            float t2 = red[0][row][1] + red[1][row][1] + red[2][row][1] + red[3][row][1];
            const float mu  = t1 * (1.f / D_);
            float var = t2 * (1.f / D_) - mu * mu;
            if (var < 0.f) var = 0.f;
            const float rs = rsqrtf(var + 1e-5f);
            bf16* xo = xout + (size_t)(m0 + row) * D_ + wc + ec;
#pragma unroll
            for (int j = 0; j < 8; ++j) {
                const int col = wc + j*16 + ec;
                float o = (acc[i][j][r] - mu) * rs * g[col] + b[col];
                xo[j*16] = __float2bfloat16(o);
            }
        }
    }
}

// ---------------------------------------------------------------------------
// Attention: block per (window, head); bf16 qkv in, bf16 ctx out; fp32 inside.
// LDS rows padded to DHP=65 floats (R5 bank-conflict fix).
// ---------------------------------------------------------------------------
__global__ __launch_bounds__(256) void attn_kernel(
    const bf16* __restrict__ qkv,
    bf16* __restrict__ ctx)
{
    const int n = blockIdx.x;
    const int h = blockIdx.y;
    __shared__ float q[W_][DHP];
    __shared__ float k[W_][DHP];
    __shared__ float v[W_][DHP];
    __shared__ float s[W_][W_ + 1];

    const int tid = threadIdx.x;
    {
        int r  = tid >> 3;
        int c0 = (tid & 7) * 8;
        const bf16* base = qkv + (size_t)(n*W_ + r) * (3*D_) + h*DH_ + c0;
        bf16x8 tq = *(const bf16x8*)(base);
        bf16x8 tk = *(const bf16x8*)(base + D_);
        bf16x8 tv = *(const bf16x8*)(base + 2*D_);
#pragma unroll
        for (int j = 0; j < 8; ++j) {
            q[r][c0 + j] = bf2f(tq[j]);
            k[r][c0 + j] = bf2f(tk[j]);
            v[r][c0 + j] = bf2f(tv[j]);
        }
    }
    __syncthreads();

    const int i = tid >> 3;
    {
        int j0 = (tid & 7) * 4;
#pragma unroll
        for (int jj = 0; jj < 4; ++jj) {
            int j = j0 + jj;
            float d = 0.f;
#pragma unroll
            for (int kk = 0; kk < DH_; ++kk) d += q[i][kk] * k[j][kk];
            s[i][j] = (j <= i) ? d * 0.125f : -1e30f;
        }
    }
    __syncthreads();

    if (tid < W_) {
        float mx = -1e30f;
#pragma unroll
        for (int j = 0; j < W_; ++j) mx = fmaxf(mx, s[tid][j]);
        float sum = 0.f;
#pragma unroll
        for (int j = 0; j < W_; ++j) { float e = __expf(s[tid][j] - mx); s[tid][j] = e; sum += e; }
        float inv = 1.f / sum;
#pragma unroll
        for (int j = 0; j < W_; ++j) s[tid][j] *= inv;
    }
    __syncthreads();

    {
        int d0 = (tid & 7) * 8;
        float o[8] = {0,0,0,0,0,0,0,0};
#pragma unroll
        for (int j = 0; j < W_; ++j) {
            float a = s[i][j];
#pragma unroll
            for (int dd = 0; dd < 8; ++dd) o[dd] += a * v[j][d0 + dd];
        }
        bf16* dst = ctx + (size_t)(n*W_ + i) * D_ + h*DH_ + d0;
#pragma unroll
        for (int dd = 0; dd < 8; ++dd) dst[dd] = __float2bfloat16(o[dd]);
    }
}

// ---------------------------------------------------------------------------
// Head: token = xb[n*32+31,:] bf16; logits (NWIN,6) then values (NWIN)
// ---------------------------------------------------------------------------
__global__ __launch_bounds__(64) void head_kernel(
    const bf16* __restrict__ xb,
    const float* __restrict__ Wp, const float* __restrict__ bp,
    const float* __restrict__ Wv, const float* __restrict__ bv,
    float* __restrict__ out)
{
    const int n    = blockIdx.x;
    const int lane = threadIdx.x;
    const bf16* row = xb + (size_t)(n*W_ + (W_-1)) * D_;
    float t[8];
#pragma unroll
    for (int j = 0; j < 8; ++j) t[j] = bf2f(*(const short*)(row + lane + j*64));

    for (int a = 0; a < A_ + 1; ++a) {
        const float* w = (a < A_) ? (Wp + (size_t)a * D_) : Wv;
        float d = 0.f;
#pragma unroll
        for (int j = 0; j < 8; ++j) d += t[j] * w[lane + j*64];
#pragma unroll
        for (int off = 32; off > 0; off >>= 1) d += __shfl_down(d, off);
        if (lane == 0) {
            if (a < A_) out[(size_t)n*A_ + a] = d + bp[a];
            else        out[(size_t)NWIN*A_ + n] = d + bv[0];
        }
    }
}

// ---------------------------------------------------------------------------
extern "C" void kernel_launch(void* const* d_in, const int* in_sizes, int n_in,
                              void* d_out, int out_size, void* d_ws, size_t ws_size,
                              hipStream_t stream) {
    const float* feats = (const float*)d_in[0];
    const float* pos   = (const float*)d_in[1];
    const float* Wqkv  = (const float*)d_in[2];
    const float* bqkv  = (const float*)d_in[3];
    const float* Wo    = (const float*)d_in[4];
    const float* bo    = (const float*)d_in[5];
    const float* ln1g  = (const float*)d_in[6];
    const float* ln1b  = (const float*)d_in[7];
    const float* W1    = (const float*)d_in[8];
    const float* b1    = (const float*)d_in[9];
    const float* W2    = (const float*)d_in[10];
    const float* b2    = (const float*)d_in[11];
    const float* ln2g  = (const float*)d_in[12];
    const float* ln2b  = (const float*)d_in[13];
    const float* Wp    = (const float*)d_in[14];
    const float* bp    = (const float*)d_in[15];
    const float* Wv    = (const float*)d_in[16];
    const float* bv    = (const float*)d_in[17];
    float* out = (float*)d_out;

    char* basep = (ws_size >= TOTAL_BYTES) ? (char*)d_ws : g_fallback;

    bf16*  xb   = (bf16*)basep;
    bf16*  wq_b = (bf16*)(basep + XB_BYTES);
    bf16*  wo_b = wq_b + WQ_ELEMS;
    bf16*  w1_b = wo_b + WO_ELEMS;
    bf16*  w2_b = w1_b + W1_ELEMS;
    bf16*  scr  = w2_b + W2_ELEMS;
    bf16*  qkv_s = scr;                            // (NTOK, 1536)
    bf16*  ctx_s = scr + (size_t)NTOK * (3*D_);    // (NTOK, 512)
    bf16*  h_s   = scr;                            // (NTOK, 2048) FFN phase

    cvt_kernel<<<(WQ_ELEMS/4 + 255)/256, 256, 0, stream>>>(Wqkv, wq_b, WQ_ELEMS/4);
    cvt_kernel<<<(WO_ELEMS/4 + 255)/256, 256, 0, stream>>>(Wo,   wo_b, WO_ELEMS/4);
    cvt_kernel<<<(W1_ELEMS/4 + 255)/256, 256, 0, stream>>>(W1,   w1_b, W1_ELEMS/4);
    cvt_kernel<<<(W2_ELEMS/4 + 255)/256, 256, 0, stream>>>(W2,   w2_b, W2_ELEMS/4);

    build_x_kernel<<<NTOK * (D_/4) / 256, 256, 0, stream>>>(feats, pos, xb);

    const int GM = NTOK / 128;   // 512 m-blocks (div by 8, XCD remap ok)

    for (int i = 0; i < L_; ++i) {
        const bf16*  wq_i = wq_b + (size_t)i * 3*D_*D_;
        const float* bq_i = bqkv + (size_t)i * 3*D_;
        const bf16*  wo_i = wo_b + (size_t)i * D_*D_;
        const float* bo_i = bo   + (size_t)i * D_;
        const bf16*  w1_i = w1_b + (size_t)i * 4*D_*D_;
        const float* b1_i = b1   + (size_t)i * 4*D_;
        const bf16*  w2_i = w2_b + (size_t)i * 4*D_*D_;
        const float* b2_i = b2   + (size_t)i * D_;

        // qkv = xb @ Wqkv^T + bqkv
        gemm_bf16<false><<<GM * (3*D_/128), 256, 0, stream>>>(
            xb, wq_i, bq_i, qkv_s, NTOK, 3*D_, D_);
        attn_kernel<<<dim3(NWIN, H_), 256, 0, stream>>>(qkv_s, ctx_s);
        // xb = LN1(xb + ctx @ Wo^T + bo)   (fused, in place)
        gemm_ln<<<NTOK/32, 256, 0, stream>>>(
            ctx_s, wo_i, bo_i, xb, xb,
            ln1g + (size_t)i*D_, ln1b + (size_t)i*D_, D_);
        // h = relu(xb @ W1^T + b1)
        gemm_bf16<true><<<GM * (4*D_/128), 256, 0, stream>>>(
            xb, w1_i, b1_i, h_s, NTOK, 4*D_, D_);
        // xb = LN2(xb + h @ W2^T + b2)     (fused, in place)
        gemm_ln<<<NTOK/32, 256, 0, stream>>>(
            h_s, w2_i, b2_i, xb, xb,
            ln2g + (size_t)i*D_, ln2b + (size_t)i*D_, 4*D_);
    }

    head_kernel<<<NWIN, 64, 0, stream>>>(xb, Wp, bp, Wv, bv, out);
}